// Round 12
// baseline (1125.799 us; speedup 1.0000x reference)
//
#include <hip/hip_runtime.h>

typedef _Float16 hx8 __attribute__((ext_vector_type(8)));
typedef float    fx4 __attribute__((ext_vector_type(4)));

constexpr int T_ = 4608;   // tokens = 8*576
constexpr int D_ = 1024;
constexpr int H_ = 4096;
constexpr int C_ = 4096;
constexpr int E_ = 8;
constexpr int PADROWS = T_ * 2 + E_ * 256;   // 11264 (256-padded buckets)
constexpr int MAXRT256 = 44;

constexpr int NBC1 = 1024, NBC3 = 1024;               // cvt13 blocks (256 thr)
constexpr int NB_CVT13 = NBC1 + NBC3;                 // 2048
constexpr int NG1 = 8 * 32 * ((MAXRT256 + 7) / 8);    // 1536 gemm1 slots
constexpr int NCVT2F = 2048;                          // w2-cvt blocks inside F (512 thr)
constexpr int NBF = 2 * NG1 + (NCVT2F - NG1);         // 3584 fused blocks

// global -> LDS direct (16B/lane), dest = wave-uniform base + lane*16
__device__ __forceinline__ void gload16(const void* g, void* l) {
    __builtin_amdgcn_global_load_lds(
        (const __attribute__((address_space(1))) void*)g,
        (__attribute__((address_space(3))) void*)l, 16, 0, 0);
}

__device__ __forceinline__ hx8 pack8(fx4 a, fx4 b) {
    hx8 h;
    h[0]=(_Float16)a[0]; h[1]=(_Float16)a[1]; h[2]=(_Float16)a[2]; h[3]=(_Float16)a[3];
    h[4]=(_Float16)b[0]; h[5]=(_Float16)b[1]; h[6]=(_Float16)b[2]; h[7]=(_Float16)b[3];
    return h;
}

// grid-strided fp32 -> fp16 convert, 4 independent chunks per iteration (MLP x4)
template <int TPB>
__device__ __forceinline__ void cvt_ilp4(const float* __restrict__ s,
                                         _Float16* __restrict__ d,
                                         int n8, int bidx, int nblocks)
{
    const fx4* s4 = (const fx4*)s;
    hx8* d8 = (hx8*)d;
    const int S = nblocks * TPB;
    int i = bidx * TPB + (int)threadIdx.x;
    for (; i + 3 * S < n8; i += 4 * S) {
        const size_t i0 = i, i1 = i + S, i2 = i + 2 * S, i3 = i + 3 * S;
        fx4 a0 = s4[2*i0], b0 = s4[2*i0+1];
        fx4 a1 = s4[2*i1], b1 = s4[2*i1+1];
        fx4 a2 = s4[2*i2], b2 = s4[2*i2+1];
        fx4 a3 = s4[2*i3], b3 = s4[2*i3+1];
        d8[i0] = pack8(a0, b0);
        d8[i1] = pack8(a1, b1);
        d8[i2] = pack8(a2, b2);
        d8[i3] = pack8(a3, b3);
    }
    for (; i < n8; i += S) {
        fx4 a = s4[2*(size_t)i], b = s4[2*(size_t)i+1];
        d8[i] = pack8(a, b);
    }
}

// ---------------- cvt13: W1/W3 fp32 -> fp16 ----------------
__global__ __launch_bounds__(256) void k_cvt13(
    const float* __restrict__ w1, _Float16* __restrict__ w1h,
    const float* __restrict__ w3, _Float16* __restrict__ w3h)
{
    const int id = blockIdx.x;
    if (id < NBC1)
        cvt_ilp4<256>(w1, w1h, E_ * H_ * D_ / 8, id, NBC1);
    else
        cvt_ilp4<256>(w3, w3h, E_ * H_ * D_ / 8, id - NBC1, NBC3);
}

// ---------------- routing: logits, top-2, softmax, x -> fp16 ----------------
__global__ __launch_bounds__(256) void k_route(
    const float* __restrict__ x, const float* __restrict__ sw,
    const float* __restrict__ sb, _Float16* __restrict__ xh,
    int* __restrict__ meta, int* __restrict__ e0a, int* __restrict__ e1a,
    float* __restrict__ w0a, float* __restrict__ w1a)
{
    __shared__ float ssw[E_ * D_];
    const int tid = threadIdx.x;
    for (int i = tid; i < E_ * D_ / 4; i += 256)
        reinterpret_cast<fx4*>(ssw)[i] = reinterpret_cast<const fx4*>(sw)[i];
    __syncthreads();

    const int wid = tid >> 6, lane = tid & 63;
    const int t = blockIdx.x * 4 + wid;
    const float* xr = x + (size_t)t * D_;
    _Float16* xhr = xh + (size_t)t * D_;

    float acc[E_] = {};
    for (int i = lane; i < D_; i += 64) {
        float xv = xr[i];
        xhr[i] = (_Float16)xv;
        #pragma unroll
        for (int e = 0; e < E_; e++) acc[e] += xv * ssw[e * D_ + i];
    }
    #pragma unroll
    for (int e = 0; e < E_; e++) {
        float v = acc[e];
        #pragma unroll
        for (int o = 32; o > 0; o >>= 1) v += __shfl_xor(v, o, 64);
        acc[e] = v;
    }
    if (lane == 0) {
        float l[E_];
        #pragma unroll
        for (int e = 0; e < E_; e++) l[e] = acc[e] + sb[e];
        int b0 = 0; float v0 = l[0];
        #pragma unroll
        for (int e = 1; e < E_; e++) if (l[e] > v0) { v0 = l[e]; b0 = e; }
        int b1 = -1; float v1 = -3.4e38f;
        #pragma unroll
        for (int e = 0; e < E_; e++) if (e != b0 && l[e] > v1) { v1 = l[e]; b1 = e; }
        float r = __expf(v1 - v0);
        float inv = 1.f / (1.f + r);
        e0a[t] = b0; e1a[t] = b1; w0a[t] = inv; w1a[t] = r * inv;
        atomicAdd(&meta[b0], 1);
        atomicAdd(&meta[b1], 1);
    }
}

// ---------------- scan: 256-padded offsets + rowtile map ----------------
// meta: [0..7]=cnt [8..15]=cursor [16..23]=padoff [24]=rows [26]=RT256 [192..235]=map256
__global__ void k_scan(int* meta)
{
    if (threadIdx.x == 0) {
        int off = 0, rt256 = 0;
        for (int e = 0; e < E_; e++) {
            meta[16 + e] = off;
            int t256 = (meta[e] + 255) / 256;
            for (int i = 0; i < t256; i++) meta[192 + rt256++] = e;
            off += t256 * 256;
        }
        meta[24] = off;
        meta[26] = rt256;
    }
}

__global__ void k_scatter(int* __restrict__ meta,
                          const int* __restrict__ e0a, const int* __restrict__ e1a,
                          const float* __restrict__ w0a, const float* __restrict__ w1a,
                          int* __restrict__ tok, float* __restrict__ gate,
                          int* __restrict__ inv)
{
    int t = blockIdx.x * 256 + threadIdx.x;
    if (t >= T_) return;
    int* cursors = meta + 8;
    const int* padoff = meta + 16;
    int e0 = e0a[t];
    int s0 = atomicAdd(&cursors[e0], 1);
    int p0 = padoff[e0] + s0;
    tok[p0] = t; gate[p0] = w0a[t]; inv[2 * t] = p0;
    int e1 = e1a[t];
    int s1 = atomicAdd(&cursors[e1], 1);
    int p1 = padoff[e1] + s1;
    tok[p1] = t; gate[p1] = w1a[t]; inv[2 * t + 1] = p1;
}

// ---------------- F: gemm1 (64KB single-buf) fused with W2 cvt ----------------
// gemm1: 256 rows x 128 hcols (x2 matrices), BK=64, 8 waves; stage->sync->compute.
// cvt blocks (no LDS use) co-reside: 64+64 KB = 2 blocks/CU, cvt waves hide
// gemm1's single-buffer load latency. 1:1 block interleave.
__global__ __launch_bounds__(512, 2) void k_g1cvt2(
    const _Float16* __restrict__ xh,
    const _Float16* __restrict__ w1h, const float* __restrict__ b1,
    const _Float16* __restrict__ w3h, const float* __restrict__ b3,
    const float* __restrict__ w2, _Float16* __restrict__ w2h,
    const int* __restrict__ meta, const int* __restrict__ tok,
    _Float16* __restrict__ hbuf)
{
    const int id = blockIdx.x;
    int sub;
    bool isg;
    if (id < 2 * NG1) { isg = !(id & 1); sub = id >> 1; }
    else             { isg = false;     sub = NG1 + (id - 2 * NG1); }

    if (!isg) {
        cvt_ilp4<512>(w2, w2h, E_ * C_ * H_ / 8, sub, NCVT2F);
        return;
    }

    const int b = sub;
    const int g = b >> 3;
    const int r = (g >> 5) * 8 + (b & 7);
    const int c = g & 31;
    if (r >= meta[26]) return;
    const int e = meta[192 + r];
    const int prow0 = r * 256;
    const int col0 = c * 128;

    extern __shared__ _Float16 smem[];        // 64 KiB
    _Float16* sA  = smem;                     // 256*64 halves
    _Float16* sB1 = smem + 16384;             // 128*64
    _Float16* sB3 = smem + 24576;             // 128*64

    const int tid = threadIdx.x;
    const int w = tid >> 6, l = tid & 63;
    const int arow = tid >> 3;                // 0..63
    const int swizh = 8 * ((tid & 7) ^ (arow & 7));
    const int wv8 = w * 8;

    const _Float16* aSrc[4];
    #pragma unroll
    for (int p = 0; p < 4; ++p) {
        const int t = tok[prow0 + p * 64 + arow];   // pad rows -> token 0 (memset)
        aSrc[p] = xh + (size_t)t * D_ + swizh;
    }
    const _Float16* b1S = w1h + ((size_t)e * H_ + col0 + arow) * D_ + swizh;
    const _Float16* b3S = w3h + ((size_t)e * H_ + col0 + arow) * D_ + swizh;

    const int wm = w >> 2, wn = w & 3;
    const int fr = l & 15, q4 = l >> 4;

    fx4 acc1[8][2] = {}, acc3[8][2] = {};

    for (int t = 0; t < D_ / 64; ++t) {
        const int kk = t * 64;
        __builtin_amdgcn_s_barrier();          // prior compute done reading
        #pragma unroll
        for (int p = 0; p < 4; ++p)
            gload16(aSrc[p] + kk, &sA[(p * 64 + wv8) * 64]);
        #pragma unroll
        for (int p = 0; p < 2; ++p) {
            gload16(b1S + (size_t)(p * 64) * D_ + kk, &sB1[(p * 64 + wv8) * 64]);
            gload16(b3S + (size_t)(p * 64) * D_ + kk, &sB3[(p * 64 + wv8) * 64]);
        }
        asm volatile("s_waitcnt vmcnt(0)" ::: "memory");
        __builtin_amdgcn_s_barrier();
        hx8 bf1[2][2], bf3[2][2];
        #pragma unroll
        for (int q = 0; q < 4; ++q) {
            hx8 af[2][2];
            #pragma unroll
            for (int mi = 0; mi < 2; ++mi)
                #pragma unroll
                for (int kh = 0; kh < 2; ++kh) {
                    const int R = wm * 128 + q * 32 + mi * 16 + fr;
                    af[mi][kh] = *(const hx8*)&sA[R * 64 + 8 * (((kh << 2) + q4) ^ (R & 7))];
                }
            if (q == 0) {
                #pragma unroll
                for (int ni = 0; ni < 2; ++ni)
                    #pragma unroll
                    for (int kh = 0; kh < 2; ++kh) {
                        const int Rc = wn * 32 + ni * 16 + fr;
                        bf1[ni][kh] = *(const hx8*)&sB1[Rc * 64 + 8 * (((kh << 2) + q4) ^ (Rc & 7))];
                        bf3[ni][kh] = *(const hx8*)&sB3[Rc * 64 + 8 * (((kh << 2) + q4) ^ (Rc & 7))];
                    }
            }
            __builtin_amdgcn_s_setprio(1);
            #pragma unroll
            for (int ni = 0; ni < 2; ++ni)
                #pragma unroll
                for (int mi = 0; mi < 2; ++mi) {
                    acc1[q * 2 + mi][ni] = __builtin_amdgcn_mfma_f32_16x16x32_f16(af[mi][0], bf1[ni][0], acc1[q * 2 + mi][ni], 0, 0, 0);
                    acc1[q * 2 + mi][ni] = __builtin_amdgcn_mfma_f32_16x16x32_f16(af[mi][1], bf1[ni][1], acc1[q * 2 + mi][ni], 0, 0, 0);
                    acc3[q * 2 + mi][ni] = __builtin_amdgcn_mfma_f32_16x16x32_f16(af[mi][0], bf3[ni][0], acc3[q * 2 + mi][ni], 0, 0, 0);
                    acc3[q * 2 + mi][ni] = __builtin_amdgcn_mfma_f32_16x16x32_f16(af[mi][1], bf3[ni][1], acc3[q * 2 + mi][ni], 0, 0, 0);
                }
            __builtin_amdgcn_s_setprio(0);
        }
    }

    #pragma unroll
    for (int ni = 0; ni < 2; ++ni) {
        const int col = col0 + wn * 32 + ni * 16 + fr;
        const float bb1 = b1[(size_t)e * H_ + col];
        const float bb3 = b3[(size_t)e * H_ + col];
        #pragma unroll
        for (int rf = 0; rf < 8; ++rf) {
            const int rowb = prow0 + wm * 128 + rf * 16 + q4 * 4;
            #pragma unroll
            for (int j = 0; j < 4; ++j) {
                float v1 = acc1[rf][ni][j] + bb1;
                float v3 = acc3[rf][ni][j] + bb3;
                float hv = v1 * v3 / (1.f + __expf(-v1));
                hbuf[(size_t)(rowb + j) * H_ + col] = (_Float16)hv;
            }
        }
    }
}

// ---------------- GEMM2: part = h W2^T + b2 ----------------
// 256x256 tile, BK=64, 8-phase counted-vmcnt schedule (round-11 proven body).
// New block map: XCD x owns c-pair {2x,2x+1} -> L2-live W2h ~= 4 MB (was ~33 MB).
__global__ __launch_bounds__(512, 2) void k_gemm2(
    const _Float16* __restrict__ hbuf, const _Float16* __restrict__ w2h,
    const float* __restrict__ b2, const int* __restrict__ meta,
    _Float16* __restrict__ part)
{
    const int b = blockIdx.x;
    const int x = b & 7;               // XCD
    const int g = b >> 3;
    const int octet = g >> 4;
    const int sub = g & 15;
    const int r = octet * 8 + (sub >> 1);
    const int c = x * 2 + (sub & 1);
    if (r >= meta[26]) return;
    const int e = meta[192 + r];
    const int prow0 = r * 256;
    const int col0 = c * 256;

    extern __shared__ _Float16 smem[];        // 128 KiB
    _Float16* sA = smem;                      // [2][256*64]
    _Float16* sB = smem + 2 * 256 * 64;       // [2][256*64]

    const int tid = threadIdx.x;
    const int w = tid >> 6, l = tid & 63;
    const int arow = tid >> 3;                // 0..63
    const int swizh = 8 * ((tid & 7) ^ (arow & 7));
    const _Float16* aS = hbuf + (size_t)(prow0 + arow) * H_ + swizh;
    const _Float16* bS = w2h + ((size_t)e * C_ + col0 + arow) * H_ + swizh;
    const int wv8 = w * 8;

    const int wm = w >> 2, wn = w & 3;
    const int fr = l & 15, q4 = l >> 4;

    fx4 acc[8][4] = {};
    hx8 bf[4][2];

    #define STG_A0(buf, kk) { gload16(aS + (size_t)(kk), &sA[(buf)*16384 + (wv8)*64]); \
                              gload16(aS + (size_t)64*H_ + (kk), &sA[(buf)*16384 + (64+wv8)*64]); }
    #define STG_A1(buf, kk) { gload16(aS + (size_t)128*H_ + (kk), &sA[(buf)*16384 + (128+wv8)*64]); \
                              gload16(aS + (size_t)192*H_ + (kk), &sA[(buf)*16384 + (192+wv8)*64]); }
    #define STG_B0(buf, kk) { gload16(bS + (size_t)(kk), &sB[(buf)*16384 + (wv8)*64]); \
                              gload16(bS + (size_t)64*H_ + (kk), &sB[(buf)*16384 + (64+wv8)*64]); }
    #define STG_B1(buf, kk) { gload16(bS + (size_t)128*H_ + (kk), &sB[(buf)*16384 + (128+wv8)*64]); \
                              gload16(bS + (size_t)192*H_ + (kk), &sB[(buf)*16384 + (192+wv8)*64]); }

    #define RD_BF(buf)                                                        \
        _Pragma("unroll")                                                     \
        for (int ni = 0; ni < 4; ++ni)                                        \
            _Pragma("unroll")                                                 \
            for (int kh = 0; kh < 2; ++kh) {                                  \
                const int Rc = wn * 64 + ni * 16 + fr;                        \
                bf[ni][kh] = *(const hx8*)&sB[(buf)*16384 + Rc * 64 + 8 * (((kh << 2) + q4) ^ (Rc & 7))]; \
            }

    #define G2PHASE(buf, q, WAITSTMT, ...) {                                  \
        hx8 af[2][2];                                                         \
        _Pragma("unroll")                                                     \
        for (int mi = 0; mi < 2; ++mi)                                        \
            _Pragma("unroll")                                                 \
            for (int kh = 0; kh < 2; ++kh) {                                  \
                const int R = wm * 128 + (q) * 32 + mi * 16 + fr;             \
                af[mi][kh] = *(const hx8*)&sA[(buf)*16384 + R * 64 + 8 * (((kh << 2) + q4) ^ (R & 7))]; \
            }                                                                 \
        __VA_ARGS__                                                           \
        __builtin_amdgcn_s_barrier();                                         \
        __builtin_amdgcn_s_setprio(1);                                        \
        _Pragma("unroll")                                                     \
        for (int ni = 0; ni < 4; ++ni)                                        \
            _Pragma("unroll")                                                 \
            for (int mi = 0; mi < 2; ++mi) {                                  \
                acc[(q)*2+mi][ni] = __builtin_amdgcn_mfma_f32_16x16x32_f16(af[mi][0], bf[ni][0], acc[(q)*2+mi][ni], 0, 0, 0); \
                acc[(q)*2+mi][ni] = __builtin_amdgcn_mfma_f32_16x16x32_f16(af[mi][1], bf[ni][1], acc[(q)*2+mi][ni], 0, 0, 0); \
            }                                                                 \
        __builtin_amdgcn_s_setprio(0);                                        \
        WAITSTMT;                                                             \
        __builtin_amdgcn_s_barrier(); }

    STG_B0(0, 0) STG_B1(0, 0) STG_A0(0, 0) STG_A1(0, 0)
    STG_B0(1, 64) STG_B1(1, 64)
    asm volatile("s_waitcnt vmcnt(4)" ::: "memory");
    __builtin_amdgcn_s_barrier();

    for (int i = 0; i < 31; ++i) {
        const int kk0 = i * 128;
        RD_BF(0)
        G2PHASE(0, 0, , STG_A0(1, kk0 + 64))
        G2PHASE(0, 1, , STG_A1(1, kk0 + 64))
        G2PHASE(0, 2, , STG_B0(0, kk0 + 128))
        G2PHASE(0, 3, asm volatile("s_waitcnt vmcnt(4)" ::: "memory"), STG_B1(0, kk0 + 128))
        RD_BF(1)
        G2PHASE(1, 0, , STG_A0(0, kk0 + 128))
        G2PHASE(1, 1, , STG_A1(0, kk0 + 128))
        G2PHASE(1, 2, , STG_B0(1, kk0 + 192))
        G2PHASE(1, 3, asm volatile("s_waitcnt vmcnt(4)" ::: "memory"), STG_B1(1, kk0 + 192))
    }
    RD_BF(0)
    G2PHASE(0, 0, , STG_A0(1, 4032))
    G2PHASE(0, 1, , STG_A1(1, 4032))
    G2PHASE(0, 2, , )
    G2PHASE(0, 3, asm volatile("s_waitcnt vmcnt(0)" ::: "memory"), )
    RD_BF(1)
    G2PHASE(1, 0, , )
    G2PHASE(1, 1, , )
    G2PHASE(1, 2, , )
    G2PHASE(1, 3, , )

    #pragma unroll
    for (int ni = 0; ni < 4; ++ni) {
        const int col = col0 + wn * 64 + ni * 16 + fr;
        const float bb = b2[(size_t)e * C_ + col];
        #pragma unroll
        for (int rf = 0; rf < 8; ++rf) {
            const int rowb = prow0 + wm * 128 + rf * 16 + q4 * 4;
            #pragma unroll
            for (int j = 0; j < 4; ++j)
                part[(size_t)(rowb + j) * C_ + col] = (_Float16)(acc[rf][ni][j] + bb);
        }
    }
    #undef STG_A0
    #undef STG_A1
    #undef STG_B0
    #undef STG_B1
    #undef RD_BF
    #undef G2PHASE
}

// ---------------- combine: out[t] = g0*part[inv0] + g1*part[inv1] ----------------
__global__ __launch_bounds__(256) void k_combine(
    const _Float16* __restrict__ part, const int* __restrict__ inv,
    const float* __restrict__ gate, float* __restrict__ out)
{
    const int bid = blockIdx.x;               // T_*2 blocks
    const int t = bid >> 1;
    const int c0 = ((bid & 1) << 11) + ((int)threadIdx.x << 3);
    const int p0 = inv[2 * t], p1 = inv[2 * t + 1];
    const float g0 = gate[p0], g1 = gate[p1];
    hx8 a = *(const hx8*)(part + (size_t)p0 * C_ + c0);
    hx8 b = *(const hx8*)(part + (size_t)p1 * C_ + c0);
    fx4 o0, o1;
    #pragma unroll
    for (int j = 0; j < 4; j++) {
        o0[j] = g0 * (float)a[j]     + g1 * (float)b[j];
        o1[j] = g0 * (float)a[4 + j] + g1 * (float)b[4 + j];
    }
    *(fx4*)(out + (size_t)t * C_ + c0)     = o0;
    *(fx4*)(out + (size_t)t * C_ + c0 + 4) = o1;
}

// ---------------- launch ----------------
extern "C" void kernel_launch(void* const* d_in, const int* in_sizes, int n_in,
                              void* d_out, int out_size, void* d_ws, size_t ws_size,
                              hipStream_t stream)
{
    const float* x  = (const float*)d_in[0];
    const float* sw = (const float*)d_in[1];
    const float* sb = (const float*)d_in[2];
    const float* w1 = (const float*)d_in[3];
    const float* b1 = (const float*)d_in[4];
    const float* w2 = (const float*)d_in[5];
    const float* b2 = (const float*)d_in[6];
    const float* w3 = (const float*)d_in[7];
    const float* b3 = (const float*)d_in[8];
    float* out = (float*)d_out;

    char* ws = (char*)d_ws;
    const size_t OFF_META = 0;                                    // 2048 B
    const size_t OFF_E0   = 2048;
    const size_t OFF_E1   = OFF_E0 + 4 * (size_t)T_;
    const size_t OFF_W0   = OFF_E1 + 4 * (size_t)T_;
    const size_t OFF_W1A  = OFF_W0 + 4 * (size_t)T_;
    const size_t OFF_TOK  = OFF_W1A + 4 * (size_t)T_;
    const size_t OFF_GATE = OFF_TOK + 4 * (size_t)PADROWS;
    const size_t OFF_INV  = OFF_GATE + 4 * (size_t)PADROWS;
    const size_t OFF_XH   = OFF_INV + 8 * (size_t)T_;
    const size_t OFF_HBUF = OFF_XH + 2 * (size_t)T_ * D_;
    // ALIAS region: w1h+w3h (live: cvt13..g1cvt2) overlaps part (live: gemm2..combine)
    const size_t OFF_ALIAS = OFF_HBUF + 2 * (size_t)PADROWS * H_;
    const size_t SZ_ALIAS  = 4 * (size_t)E_ * H_ * D_;            // 128 MiB
    const size_t OFF_W2H   = OFF_ALIAS + SZ_ALIAS;

    int*      meta  = (int*)(ws + OFF_META);
    int*      e0a   = (int*)(ws + OFF_E0);
    int*      e1a   = (int*)(ws + OFF_E1);
    float*    w0a   = (float*)(ws + OFF_W0);
    float*    w1a   = (float*)(ws + OFF_W1A);
    int*      tokb  = (int*)(ws + OFF_TOK);
    float*    gateb = (float*)(ws + OFF_GATE);
    int*      invb  = (int*)(ws + OFF_INV);
    _Float16* xh    = (_Float16*)(ws + OFF_XH);
    _Float16* hbuf  = (_Float16*)(ws + OFF_HBUF);
    _Float16* w1h   = (_Float16*)(ws + OFF_ALIAS);
    _Float16* w3h   = (_Float16*)(ws + OFF_ALIAS + 2 * (size_t)E_ * H_ * D_);
    _Float16* partb = (_Float16*)(ws + OFF_ALIAS);                // reuses w1h/w3h space
    _Float16* w2h   = (_Float16*)(ws + OFF_W2H);

    hipMemsetAsync(meta, 0, 2048, stream);
    hipMemsetAsync(tokb, 0, 4 * (size_t)PADROWS, stream);

    k_route<<<T_ / 4, 256, 0, stream>>>(x, sw, sb, xh, meta, e0a, e1a, w0a, w1a);
    k_cvt13<<<NB_CVT13, 256, 0, stream>>>(w1, w1h, w3, w3h);
    k_scan<<<1, 1, 0, stream>>>(meta);
    k_scatter<<<(T_ + 255) / 256, 256, 0, stream>>>(meta, e0a, e1a, w0a, w1a,
                                                    tokb, gateb, invb);
    k_g1cvt2<<<NBF, 512, 65536, stream>>>(xh, w1h, b1, w3h, b3, w2, w2h,
                                          meta, tokb, hbuf);
    k_gemm2<<<8 * 16 * ((MAXRT256 + 7) / 8), 512, 131072, stream>>>(
        hbuf, w2h, b2, meta, partb);
    k_combine<<<T_ * 2, 256, 0, stream>>>(partb, invb, gateb, out);
}

// Round 13
// 931.411 us; speedup vs baseline: 1.2087x; 1.2087x over previous
//
#include <hip/hip_runtime.h>

typedef _Float16 hx8 __attribute__((ext_vector_type(8)));
typedef float    fx4 __attribute__((ext_vector_type(4)));

constexpr int T_ = 4608;   // tokens = 8*576
constexpr int D_ = 1024;
constexpr int H_ = 4096;
constexpr int C_ = 4096;
constexpr int E_ = 8;
constexpr int PADROWS = T_ * 2 + E_ * 256;   // 11264 (256-padded buckets)
constexpr int MAXRT256 = 44;

constexpr int NBC1 = 1024, NBC3 = 1024;               // cvt13 blocks (256 thr)
constexpr int NB_CVT13 = NBC1 + NBC3;                 // 2048
constexpr int NG1 = 8 * 32 * ((MAXRT256 + 7) / 8);    // 1536 gemm1 blocks
constexpr int N8W2 = E_ * C_ * H_ / 8;                // 16777216 hx8 chunks of W2
constexpr int CPB = (N8W2 + NG1 - 1) / NG1;           // 10923 chunks per block
// per-thread chunk count: ceil(10923/512)=22 -> 2 chunks/K-iter for t=0..10

// global -> LDS direct (16B/lane), dest = wave-uniform base + lane*16
__device__ __forceinline__ void gload16(const void* g, void* l) {
    __builtin_amdgcn_global_load_lds(
        (const __attribute__((address_space(1))) void*)g,
        (__attribute__((address_space(3))) void*)l, 16, 0, 0);
}

__device__ __forceinline__ hx8 pack8(fx4 a, fx4 b) {
    hx8 h;
    h[0]=(_Float16)a[0]; h[1]=(_Float16)a[1]; h[2]=(_Float16)a[2]; h[3]=(_Float16)a[3];
    h[4]=(_Float16)b[0]; h[5]=(_Float16)b[1]; h[6]=(_Float16)b[2]; h[7]=(_Float16)b[3];
    return h;
}

// grid-strided fp32 -> fp16 convert, 4 independent chunks per iteration (MLP x4)
template <int TPB>
__device__ __forceinline__ void cvt_ilp4(const float* __restrict__ s,
                                         _Float16* __restrict__ d,
                                         int n8, int bidx, int nblocks)
{
    const fx4* s4 = (const fx4*)s;
    hx8* d8 = (hx8*)d;
    const int S = nblocks * TPB;
    int i = bidx * TPB + (int)threadIdx.x;
    for (; i + 3 * S < n8; i += 4 * S) {
        const size_t i0 = i, i1 = i + S, i2 = i + 2 * S, i3 = i + 3 * S;
        fx4 a0 = s4[2*i0], b0 = s4[2*i0+1];
        fx4 a1 = s4[2*i1], b1 = s4[2*i1+1];
        fx4 a2 = s4[2*i2], b2 = s4[2*i2+1];
        fx4 a3 = s4[2*i3], b3 = s4[2*i3+1];
        d8[i0] = pack8(a0, b0);
        d8[i1] = pack8(a1, b1);
        d8[i2] = pack8(a2, b2);
        d8[i3] = pack8(a3, b3);
    }
    for (; i < n8; i += S) {
        fx4 a = s4[2*(size_t)i], b = s4[2*(size_t)i+1];
        d8[i] = pack8(a, b);
    }
}

// ---------------- cvt13: W1/W3 fp32 -> fp16 ----------------
__global__ __launch_bounds__(256) void k_cvt13(
    const float* __restrict__ w1, _Float16* __restrict__ w1h,
    const float* __restrict__ w3, _Float16* __restrict__ w3h)
{
    const int id = blockIdx.x;
    if (id < NBC1)
        cvt_ilp4<256>(w1, w1h, E_ * H_ * D_ / 8, id, NBC1);
    else
        cvt_ilp4<256>(w3, w3h, E_ * H_ * D_ / 8, id - NBC1, NBC3);
}

// ---------------- routing: logits, top-2, softmax, x -> fp16 ----------------
__global__ __launch_bounds__(256) void k_route(
    const float* __restrict__ x, const float* __restrict__ sw,
    const float* __restrict__ sb, _Float16* __restrict__ xh,
    int* __restrict__ meta, int* __restrict__ e0a, int* __restrict__ e1a,
    float* __restrict__ w0a, float* __restrict__ w1a)
{
    __shared__ float ssw[E_ * D_];
    const int tid = threadIdx.x;
    for (int i = tid; i < E_ * D_ / 4; i += 256)
        reinterpret_cast<fx4*>(ssw)[i] = reinterpret_cast<const fx4*>(sw)[i];
    __syncthreads();

    const int wid = tid >> 6, lane = tid & 63;
    const int t = blockIdx.x * 4 + wid;
    const float* xr = x + (size_t)t * D_;
    _Float16* xhr = xh + (size_t)t * D_;

    float acc[E_] = {};
    for (int i = lane; i < D_; i += 64) {
        float xv = xr[i];
        xhr[i] = (_Float16)xv;
        #pragma unroll
        for (int e = 0; e < E_; e++) acc[e] += xv * ssw[e * D_ + i];
    }
    #pragma unroll
    for (int e = 0; e < E_; e++) {
        float v = acc[e];
        #pragma unroll
        for (int o = 32; o > 0; o >>= 1) v += __shfl_xor(v, o, 64);
        acc[e] = v;
    }
    if (lane == 0) {
        float l[E_];
        #pragma unroll
        for (int e = 0; e < E_; e++) l[e] = acc[e] + sb[e];
        int b0 = 0; float v0 = l[0];
        #pragma unroll
        for (int e = 1; e < E_; e++) if (l[e] > v0) { v0 = l[e]; b0 = e; }
        int b1 = -1; float v1 = -3.4e38f;
        #pragma unroll
        for (int e = 0; e < E_; e++) if (e != b0 && l[e] > v1) { v1 = l[e]; b1 = e; }
        float r = __expf(v1 - v0);
        float inv = 1.f / (1.f + r);
        e0a[t] = b0; e1a[t] = b1; w0a[t] = inv; w1a[t] = r * inv;
        atomicAdd(&meta[b0], 1);
        atomicAdd(&meta[b1], 1);
    }
}

// ---------------- scan: 256-padded offsets + rowtile map ----------------
// meta: [0..7]=cnt [8..15]=cursor [16..23]=padoff [24]=rows [26]=RT256 [192..235]=map256
__global__ void k_scan(int* meta)
{
    if (threadIdx.x == 0) {
        int off = 0, rt256 = 0;
        for (int e = 0; e < E_; e++) {
            meta[16 + e] = off;
            int t256 = (meta[e] + 255) / 256;
            for (int i = 0; i < t256; i++) meta[192 + rt256++] = e;
            off += t256 * 256;
        }
        meta[24] = off;
        meta[26] = rt256;
    }
}

__global__ void k_scatter(int* __restrict__ meta,
                          const int* __restrict__ e0a, const int* __restrict__ e1a,
                          const float* __restrict__ w0a, const float* __restrict__ w1a,
                          int* __restrict__ tok, float* __restrict__ gate,
                          int* __restrict__ inv)
{
    int t = blockIdx.x * 256 + threadIdx.x;
    if (t >= T_) return;
    int* cursors = meta + 8;
    const int* padoff = meta + 16;
    int e0 = e0a[t];
    int s0 = atomicAdd(&cursors[e0], 1);
    int p0 = padoff[e0] + s0;
    tok[p0] = t; gate[p0] = w0a[t]; inv[2 * t] = p0;
    int e1 = e1a[t];
    int s1 = atomicAdd(&cursors[e1], 1);
    int p1 = padoff[e1] + s1;
    tok[p1] = t; gate[p1] = w1a[t]; inv[2 * t + 1] = p1;
}

// ---------------- GEMM1 + homogeneous W2 cvt ----------------
// 256 rows x 128 hcols (x2 matrices), BK=64, 512 thr / 8 waves, dbuf 128 KiB LDS,
// counted pipeline (round-9/11 proven body). EVERY block additionally converts a
// static slice of W2 (CPB chunks), interleaved in the K-loop: loads with the
// stage, convert after MFMA, stores at next iter top (retire in compute shadow).
__global__ __launch_bounds__(512, 2) void k_g1cvt2(
    const _Float16* __restrict__ xh,
    const _Float16* __restrict__ w1h, const float* __restrict__ b1,
    const _Float16* __restrict__ w3h, const float* __restrict__ b3,
    const float* __restrict__ w2, _Float16* __restrict__ w2h,
    const int* __restrict__ meta, const int* __restrict__ tok,
    _Float16* __restrict__ hbuf)
{
    const int b = blockIdx.x;
    const int tid = threadIdx.x;

    // ---- cvt slice for this block (all blocks, uniform) ----
    const fx4* s4 = (const fx4*)w2;
    hx8* d8 = (hx8*)w2h;
    const int cBase = b * CPB;
    const int cEnd = (cBase + CPB < N8W2) ? cBase + CPB : N8W2;

    const int g = b >> 3;
    const int r = (g >> 5) * 8 + (b & 7);
    const int c = g & 31;

    if (r >= meta[26]) {
        // no gemm work: plain cvt slice
        for (int k = 0; k < 22; ++k) {
            int idx = cBase + k * 512 + tid;
            if (idx < cEnd)
                d8[idx] = pack8(s4[2 * (size_t)idx], s4[2 * (size_t)idx + 1]);
        }
        return;
    }

    const int e = meta[192 + r];
    const int prow0 = r * 256;
    const int col0 = c * 128;

    extern __shared__ _Float16 smem[];        // 128 KiB
    _Float16* sA  = smem;                     // [2][256*64]
    _Float16* sB1 = smem + 2 * 256 * 64;      // [2][128*64]
    _Float16* sB3 = sB1 + 2 * 128 * 64;       // [2][128*64]

    const int w = tid >> 6, l = tid & 63;
    const int arow = tid >> 3;                // 0..63
    const int swizh = 8 * ((tid & 7) ^ (arow & 7));
    const int wv8 = w * 8;

    const _Float16* aSrc[4];
    #pragma unroll
    for (int p = 0; p < 4; ++p) {
        const int t = tok[prow0 + p * 64 + arow];   // pad rows -> token 0 (memset)
        aSrc[p] = xh + (size_t)t * D_ + swizh;
    }
    const _Float16* b1S = w1h + ((size_t)e * H_ + col0 + arow) * D_ + swizh;
    const _Float16* b3S = w3h + ((size_t)e * H_ + col0 + arow) * D_ + swizh;

    const int wm = w >> 2, wn = w & 3;
    const int fr = l & 15, q4 = l >> 4;

    fx4 acc1[8][2] = {}, acc3[8][2] = {};

    // cvt pipeline regs (statically named; rule #20)
    fx4 cA0, cB0, cA1, cB1;
    hx8 ph0, ph1;
    int pi0 = -1, pi1 = -1;
    int ci0 = -1, ci1 = -1;

    #define G1STAGE(buf, kk)                                                        \
        _Pragma("unroll")                                                           \
        for (int p = 0; p < 4; ++p)                                                 \
            gload16(aSrc[p] + (kk), &sA[(buf) * 16384 + (p * 64 + wv8) * 64]);      \
        _Pragma("unroll")                                                           \
        for (int p = 0; p < 2; ++p) {                                               \
            gload16(b1S + (size_t)(p * 64) * D_ + (kk), &sB1[(buf) * 8192 + (p * 64 + wv8) * 64]); \
            gload16(b3S + (size_t)(p * 64) * D_ + (kk), &sB3[(buf) * 8192 + (p * 64 + wv8) * 64]); \
        }

    G1STAGE(0, 0)
    asm volatile("s_waitcnt vmcnt(0)" ::: "memory");
    __builtin_amdgcn_s_barrier();

    int cur = 0;
    for (int t = 0; t < D_ / 64; ++t) {
        // retire previous iter's cvt stores (overlap with this iter's compute)
        if (pi0 >= 0) d8[pi0] = ph0;
        if (pi1 >= 0) d8[pi1] = ph1;
        pi0 = pi1 = -1;
        if (t + 1 < D_ / 64) { G1STAGE(cur ^ 1, (t + 1) * 64) }
        // issue this iter's cvt loads (2 chunks for t<=10)
        ci0 = ci1 = -1;
        if (t <= 10) {
            int i0 = cBase + (2 * t) * 512 + tid;
            int i1 = cBase + (2 * t + 1) * 512 + tid;
            if (i0 < cEnd) { cA0 = s4[2 * (size_t)i0]; cB0 = s4[2 * (size_t)i0 + 1]; ci0 = i0; }
            if (i1 < cEnd) { cA1 = s4[2 * (size_t)i1]; cB1 = s4[2 * (size_t)i1 + 1]; ci1 = i1; }
        }
        hx8 bf1[2][2], bf3[2][2];
        #pragma unroll
        for (int q = 0; q < 4; ++q) {
            hx8 af[2][2];
            #pragma unroll
            for (int mi = 0; mi < 2; ++mi)
                #pragma unroll
                for (int kh = 0; kh < 2; ++kh) {
                    const int R = wm * 128 + q * 32 + mi * 16 + fr;
                    af[mi][kh] = *(const hx8*)&sA[cur * 16384 + R * 64 + 8 * (((kh << 2) + q4) ^ (R & 7))];
                }
            if (q == 0) {
                #pragma unroll
                for (int ni = 0; ni < 2; ++ni)
                    #pragma unroll
                    for (int kh = 0; kh < 2; ++kh) {
                        const int Rc = wn * 32 + ni * 16 + fr;
                        bf1[ni][kh] = *(const hx8*)&sB1[cur * 8192 + Rc * 64 + 8 * (((kh << 2) + q4) ^ (Rc & 7))];
                        bf3[ni][kh] = *(const hx8*)&sB3[cur * 8192 + Rc * 64 + 8 * (((kh << 2) + q4) ^ (Rc & 7))];
                    }
            }
            __builtin_amdgcn_s_setprio(1);
            #pragma unroll
            for (int ni = 0; ni < 2; ++ni)
                #pragma unroll
                for (int mi = 0; mi < 2; ++mi) {
                    acc1[q * 2 + mi][ni] = __builtin_amdgcn_mfma_f32_16x16x32_f16(af[mi][0], bf1[ni][0], acc1[q * 2 + mi][ni], 0, 0, 0);
                    acc1[q * 2 + mi][ni] = __builtin_amdgcn_mfma_f32_16x16x32_f16(af[mi][1], bf1[ni][1], acc1[q * 2 + mi][ni], 0, 0, 0);
                    acc3[q * 2 + mi][ni] = __builtin_amdgcn_mfma_f32_16x16x32_f16(af[mi][0], bf3[ni][0], acc3[q * 2 + mi][ni], 0, 0, 0);
                    acc3[q * 2 + mi][ni] = __builtin_amdgcn_mfma_f32_16x16x32_f16(af[mi][1], bf3[ni][1], acc3[q * 2 + mi][ni], 0, 0, 0);
                }
            __builtin_amdgcn_s_setprio(0);
        }
        // convert loaded chunks (VALU; MFMA pipe unaffected)
        if (ci0 >= 0) { ph0 = pack8(cA0, cB0); pi0 = ci0; }
        if (ci1 >= 0) { ph1 = pack8(cA1, cB1); pi1 = ci1; }
        asm volatile("s_waitcnt vmcnt(0)" ::: "memory");
        __builtin_amdgcn_s_barrier();
        cur ^= 1;
    }
    if (pi0 >= 0) d8[pi0] = ph0;
    if (pi1 >= 0) d8[pi1] = ph1;

    #pragma unroll
    for (int ni = 0; ni < 2; ++ni) {
        const int col = col0 + wn * 32 + ni * 16 + fr;
        const float bb1 = b1[(size_t)e * H_ + col];
        const float bb3 = b3[(size_t)e * H_ + col];
        #pragma unroll
        for (int rf = 0; rf < 8; ++rf) {
            const int rowb = prow0 + wm * 128 + rf * 16 + q4 * 4;
            #pragma unroll
            for (int j = 0; j < 4; ++j) {
                float v1 = acc1[rf][ni][j] + bb1;
                float v3 = acc3[rf][ni][j] + bb3;
                float hv = v1 * v3 / (1.f + __expf(-v1));
                hbuf[(size_t)(rowb + j) * H_ + col] = (_Float16)hv;
            }
        }
    }
    #undef G1STAGE
}

// ---------------- GEMM2: part = h W2^T + b2 ----------------
// 256x256 tile, BK=64, 8-phase counted-vmcnt schedule (round-11 proven, exact).
__global__ __launch_bounds__(512, 2) void k_gemm2(
    const _Float16* __restrict__ hbuf, const _Float16* __restrict__ w2h,
    const float* __restrict__ b2, const int* __restrict__ meta,
    _Float16* __restrict__ part)
{
    const int b = blockIdx.x;
    const int g = b >> 3;
    const int r = (g >> 4) * 8 + (b & 7);
    const int c = g & 15;
    if (r >= meta[26]) return;
    const int e = meta[192 + r];
    const int prow0 = r * 256;
    const int col0 = c * 256;

    extern __shared__ _Float16 smem[];        // 128 KiB
    _Float16* sA = smem;                      // [2][256*64]
    _Float16* sB = smem + 2 * 256 * 64;       // [2][256*64]

    const int tid = threadIdx.x;
    const int w = tid >> 6, l = tid & 63;
    const int arow = tid >> 3;                // 0..63
    const int swizh = 8 * ((tid & 7) ^ (arow & 7));
    const _Float16* aS = hbuf + (size_t)(prow0 + arow) * H_ + swizh;
    const _Float16* bS = w2h + ((size_t)e * C_ + col0 + arow) * H_ + swizh;
    const int wv8 = w * 8;

    const int wm = w >> 2, wn = w & 3;
    const int fr = l & 15, q4 = l >> 4;

    fx4 acc[8][4] = {};
    hx8 bf[4][2];

    #define STG_A0(buf, kk) { gload16(aS + (size_t)(kk), &sA[(buf)*16384 + (wv8)*64]); \
                              gload16(aS + (size_t)64*H_ + (kk), &sA[(buf)*16384 + (64+wv8)*64]); }
    #define STG_A1(buf, kk) { gload16(aS + (size_t)128*H_ + (kk), &sA[(buf)*16384 + (128+wv8)*64]); \
                              gload16(aS + (size_t)192*H_ + (kk), &sA[(buf)*16384 + (192+wv8)*64]); }
    #define STG_B0(buf, kk) { gload16(bS + (size_t)(kk), &sB[(buf)*16384 + (wv8)*64]); \
                              gload16(bS + (size_t)64*H_ + (kk), &sB[(buf)*16384 + (64+wv8)*64]); }
    #define STG_B1(buf, kk) { gload16(bS + (size_t)128*H_ + (kk), &sB[(buf)*16384 + (128+wv8)*64]); \
                              gload16(bS + (size_t)192*H_ + (kk), &sB[(buf)*16384 + (192+wv8)*64]); }

    #define RD_BF(buf)                                                        \
        _Pragma("unroll")                                                     \
        for (int ni = 0; ni < 4; ++ni)                                        \
            _Pragma("unroll")                                                 \
            for (int kh = 0; kh < 2; ++kh) {                                  \
                const int Rc = wn * 64 + ni * 16 + fr;                        \
                bf[ni][kh] = *(const hx8*)&sB[(buf)*16384 + Rc * 64 + 8 * (((kh << 2) + q4) ^ (Rc & 7))]; \
            }

    #define G2PHASE(buf, q, WAITSTMT, ...) {                                  \
        hx8 af[2][2];                                                         \
        _Pragma("unroll")                                                     \
        for (int mi = 0; mi < 2; ++mi)                                        \
            _Pragma("unroll")                                                 \
            for (int kh = 0; kh < 2; ++kh) {                                  \
                const int R = wm * 128 + (q) * 32 + mi * 16 + fr;             \
                af[mi][kh] = *(const hx8*)&sA[(buf)*16384 + R * 64 + 8 * (((kh << 2) + q4) ^ (R & 7))]; \
            }                                                                 \
        __VA_ARGS__                                                           \
        __builtin_amdgcn_s_barrier();                                         \
        __builtin_amdgcn_s_setprio(1);                                        \
        _Pragma("unroll")                                                     \
        for (int ni = 0; ni < 4; ++ni)                                        \
            _Pragma("unroll")                                                 \
            for (int mi = 0; mi < 2; ++mi) {                                  \
                acc[(q)*2+mi][ni] = __builtin_amdgcn_mfma_f32_16x16x32_f16(af[mi][0], bf[ni][0], acc[(q)*2+mi][ni], 0, 0, 0); \
                acc[(q)*2+mi][ni] = __builtin_amdgcn_mfma_f32_16x16x32_f16(af[mi][1], bf[ni][1], acc[(q)*2+mi][ni], 0, 0, 0); \
            }                                                                 \
        __builtin_amdgcn_s_setprio(0);                                        \
        WAITSTMT;                                                             \
        __builtin_amdgcn_s_barrier(); }

    STG_B0(0, 0) STG_B1(0, 0) STG_A0(0, 0) STG_A1(0, 0)
    STG_B0(1, 64) STG_B1(1, 64)
    asm volatile("s_waitcnt vmcnt(4)" ::: "memory");
    __builtin_amdgcn_s_barrier();

    for (int i = 0; i < 31; ++i) {
        const int kk0 = i * 128;
        RD_BF(0)
        G2PHASE(0, 0, , STG_A0(1, kk0 + 64))
        G2PHASE(0, 1, , STG_A1(1, kk0 + 64))
        G2PHASE(0, 2, , STG_B0(0, kk0 + 128))
        G2PHASE(0, 3, asm volatile("s_waitcnt vmcnt(4)" ::: "memory"), STG_B1(0, kk0 + 128))
        RD_BF(1)
        G2PHASE(1, 0, , STG_A0(0, kk0 + 128))
        G2PHASE(1, 1, , STG_A1(0, kk0 + 128))
        G2PHASE(1, 2, , STG_B0(1, kk0 + 192))
        G2PHASE(1, 3, asm volatile("s_waitcnt vmcnt(4)" ::: "memory"), STG_B1(1, kk0 + 192))
    }
    RD_BF(0)
    G2PHASE(0, 0, , STG_A0(1, 4032))
    G2PHASE(0, 1, , STG_A1(1, 4032))
    G2PHASE(0, 2, , )
    G2PHASE(0, 3, asm volatile("s_waitcnt vmcnt(0)" ::: "memory"), )
    RD_BF(1)
    G2PHASE(1, 0, , )
    G2PHASE(1, 1, , )
    G2PHASE(1, 2, , )
    G2PHASE(1, 3, , )

    #pragma unroll
    for (int ni = 0; ni < 4; ++ni) {
        const int col = col0 + wn * 64 + ni * 16 + fr;
        const float bb = b2[(size_t)e * C_ + col];
        #pragma unroll
        for (int rf = 0; rf < 8; ++rf) {
            const int rowb = prow0 + wm * 128 + rf * 16 + q4 * 4;
            #pragma unroll
            for (int j = 0; j < 4; ++j)
                part[(size_t)(rowb + j) * C_ + col] = (_Float16)(acc[rf][ni][j] + bb);
        }
    }
    #undef STG_A0
    #undef STG_A1
    #undef STG_B0
    #undef STG_B1
    #undef RD_BF
    #undef G2PHASE
}

// ---------------- combine: out[t] = g0*part[inv0] + g1*part[inv1] ----------------
__global__ __launch_bounds__(256) void k_combine(
    const _Float16* __restrict__ part, const int* __restrict__ inv,
    const float* __restrict__ gate, float* __restrict__ out)
{
    const int bid = blockIdx.x;               // T_*2 blocks
    const int t = bid >> 1;
    const int c0 = ((bid & 1) << 11) + ((int)threadIdx.x << 3);
    const int p0 = inv[2 * t], p1 = inv[2 * t + 1];
    const float g0 = gate[p0], g1 = gate[p1];
    hx8 a = *(const hx8*)(part + (size_t)p0 * C_ + c0);
    hx8 b = *(const hx8*)(part + (size_t)p1 * C_ + c0);
    fx4 o0, o1;
    #pragma unroll
    for (int j = 0; j < 4; j++) {
        o0[j] = g0 * (float)a[j]     + g1 * (float)b[j];
        o1[j] = g0 * (float)a[4 + j] + g1 * (float)b[4 + j];
    }
    *(fx4*)(out + (size_t)t * C_ + c0)     = o0;
    *(fx4*)(out + (size_t)t * C_ + c0 + 4) = o1;
}

// ---------------- launch ----------------
extern "C" void kernel_launch(void* const* d_in, const int* in_sizes, int n_in,
                              void* d_out, int out_size, void* d_ws, size_t ws_size,
                              hipStream_t stream)
{
    const float* x  = (const float*)d_in[0];
    const float* sw = (const float*)d_in[1];
    const float* sb = (const float*)d_in[2];
    const float* w1 = (const float*)d_in[3];
    const float* b1 = (const float*)d_in[4];
    const float* w2 = (const float*)d_in[5];
    const float* b2 = (const float*)d_in[6];
    const float* w3 = (const float*)d_in[7];
    const float* b3 = (const float*)d_in[8];
    float* out = (float*)d_out;

    char* ws = (char*)d_ws;
    const size_t OFF_META = 0;                                    // 2048 B
    const size_t OFF_E0   = 2048;
    const size_t OFF_E1   = OFF_E0 + 4 * (size_t)T_;
    const size_t OFF_W0   = OFF_E1 + 4 * (size_t)T_;
    const size_t OFF_W1A  = OFF_W0 + 4 * (size_t)T_;
    const size_t OFF_TOK  = OFF_W1A + 4 * (size_t)T_;
    const size_t OFF_GATE = OFF_TOK + 4 * (size_t)PADROWS;
    const size_t OFF_INV  = OFF_GATE + 4 * (size_t)PADROWS;
    const size_t OFF_XH   = OFF_INV + 8 * (size_t)T_;
    const size_t OFF_HBUF = OFF_XH + 2 * (size_t)T_ * D_;
    // ALIAS region: w1h+w3h (live: cvt13..g1cvt2) overlaps part (live: gemm2..combine)
    const size_t OFF_ALIAS = OFF_HBUF + 2 * (size_t)PADROWS * H_;
    const size_t SZ_ALIAS  = 4 * (size_t)E_ * H_ * D_;            // 128 MiB
    const size_t OFF_W2H   = OFF_ALIAS + SZ_ALIAS;

    int*      meta  = (int*)(ws + OFF_META);
    int*      e0a   = (int*)(ws + OFF_E0);
    int*      e1a   = (int*)(ws + OFF_E1);
    float*    w0a   = (float*)(ws + OFF_W0);
    float*    w1a   = (float*)(ws + OFF_W1A);
    int*      tokb  = (int*)(ws + OFF_TOK);
    float*    gateb = (float*)(ws + OFF_GATE);
    int*      invb  = (int*)(ws + OFF_INV);
    _Float16* xh    = (_Float16*)(ws + OFF_XH);
    _Float16* hbuf  = (_Float16*)(ws + OFF_HBUF);
    _Float16* w1h   = (_Float16*)(ws + OFF_ALIAS);
    _Float16* w3h   = (_Float16*)(ws + OFF_ALIAS + 2 * (size_t)E_ * H_ * D_);
    _Float16* partb = (_Float16*)(ws + OFF_ALIAS);                // reuses w1h/w3h space
    _Float16* w2h   = (_Float16*)(ws + OFF_W2H);

    hipMemsetAsync(meta, 0, 2048, stream);
    hipMemsetAsync(tokb, 0, 4 * (size_t)PADROWS, stream);

    k_route<<<T_ / 4, 256, 0, stream>>>(x, sw, sb, xh, meta, e0a, e1a, w0a, w1a);
    k_cvt13<<<NB_CVT13, 256, 0, stream>>>(w1, w1h, w3, w3h);
    k_scan<<<1, 1, 0, stream>>>(meta);
    k_scatter<<<(T_ + 255) / 256, 256, 0, stream>>>(meta, e0a, e1a, w0a, w1a,
                                                    tokb, gateb, invb);
    k_g1cvt2<<<NG1, 512, 131072, stream>>>(xh, w1h, b1, w3h, b3, w2, w2h,
                                           meta, tokb, hbuf);
    k_gemm2<<<8 * 16 * ((MAXRT256 + 7) / 8), 512, 131072, stream>>>(
        hbuf, w2h, b2, meta, partb);
    k_combine<<<T_ * 2, 256, 0, stream>>>(partb, invb, gateb, out);
}

// Round 14
// 907.271 us; speedup vs baseline: 1.2409x; 1.0266x over previous
//
#include <hip/hip_runtime.h>

typedef _Float16 hx8 __attribute__((ext_vector_type(8)));
typedef float    fx4 __attribute__((ext_vector_type(4)));

constexpr int T_ = 4608;   // tokens = 8*576
constexpr int D_ = 1024;
constexpr int H_ = 4096;
constexpr int C_ = 4096;
constexpr int E_ = 8;
constexpr int PADROWS = T_ * 2 + E_ * 256;   // 11264 (256-padded buckets)
constexpr int MAXRT256 = 44;

constexpr int NBCV = 2048;                            // cvt blocks per matrix (w1,w3)
constexpr int NB_PRE = 2 * NBCV + T_ / 4;             // 5248: cvt1|cvt3|route
constexpr int NG1 = 8 * 32 * ((MAXRT256 + 7) / 8);    // 1536 gemm1 blocks
constexpr int N8W2 = E_ * C_ * H_ / 8;                // 16777216 hx8 chunks of W2
constexpr int CPB = (N8W2 + NG1 - 1) / NG1;           // 10923 chunks per block

// global -> LDS direct (16B/lane), dest = wave-uniform base + lane*16
__device__ __forceinline__ void gload16(const void* g, void* l) {
    __builtin_amdgcn_global_load_lds(
        (const __attribute__((address_space(1))) void*)g,
        (__attribute__((address_space(3))) void*)l, 16, 0, 0);
}

__device__ __forceinline__ hx8 pack8(fx4 a, fx4 b) {
    hx8 h;
    h[0]=(_Float16)a[0]; h[1]=(_Float16)a[1]; h[2]=(_Float16)a[2]; h[3]=(_Float16)a[3];
    h[4]=(_Float16)b[0]; h[5]=(_Float16)b[1]; h[6]=(_Float16)b[2]; h[7]=(_Float16)b[3];
    return h;
}

// grid-strided fp32 -> fp16 convert, 4 independent chunks per iteration (MLP x4)
template <int TPB>
__device__ __forceinline__ void cvt_ilp4(const float* __restrict__ s,
                                         _Float16* __restrict__ d,
                                         int n8, int bidx, int nblocks)
{
    const fx4* s4 = (const fx4*)s;
    hx8* d8 = (hx8*)d;
    const int S = nblocks * TPB;
    int i = bidx * TPB + (int)threadIdx.x;
    for (; i + 3 * S < n8; i += 4 * S) {
        const size_t i0 = i, i1 = i + S, i2 = i + 2 * S, i3 = i + 3 * S;
        fx4 a0 = s4[2*i0], b0 = s4[2*i0+1];
        fx4 a1 = s4[2*i1], b1 = s4[2*i1+1];
        fx4 a2 = s4[2*i2], b2 = s4[2*i2+1];
        fx4 a3 = s4[2*i3], b3 = s4[2*i3+1];
        d8[i0] = pack8(a0, b0);
        d8[i1] = pack8(a1, b1);
        d8[i2] = pack8(a2, b2);
        d8[i3] = pack8(a3, b3);
    }
    for (; i < n8; i += S) {
        fx4 a = s4[2*(size_t)i], b = s4[2*(size_t)i+1];
        d8[i] = pack8(a, b);
    }
}

// ---------------- precvt: W1/W3 cvt + routing, one LDS-free launch ----------------
__global__ __launch_bounds__(256) void k_precvt(
    const float* __restrict__ x, const float* __restrict__ sw,
    const float* __restrict__ sb,
    const float* __restrict__ w1, _Float16* __restrict__ w1h,
    const float* __restrict__ w3, _Float16* __restrict__ w3h,
    _Float16* __restrict__ xh,
    int* __restrict__ meta, int* __restrict__ e0a, int* __restrict__ e1a,
    float* __restrict__ w0a, float* __restrict__ w1a)
{
    const int id = blockIdx.x;
    const int tid = threadIdx.x;

    if (id < NBCV) { cvt_ilp4<256>(w1, w1h, E_ * H_ * D_ / 8, id, NBCV); return; }
    if (id < 2 * NBCV) { cvt_ilp4<256>(w3, w3h, E_ * H_ * D_ / 8, id - NBCV, NBCV); return; }

    // route (LDS-free; sw is L2/L3-hot)
    const int wid = tid >> 6, lane = tid & 63;
    const int t = (id - 2 * NBCV) * 4 + wid;
    const float* xr = x + (size_t)t * D_;
    _Float16* xhr = xh + (size_t)t * D_;

    float acc[E_] = {};
    for (int i = lane; i < D_; i += 64) {
        float xv = xr[i];
        xhr[i] = (_Float16)xv;
        #pragma unroll
        for (int e = 0; e < E_; e++) acc[e] += xv * sw[e * D_ + i];
    }
    #pragma unroll
    for (int e = 0; e < E_; e++) {
        float v = acc[e];
        #pragma unroll
        for (int o = 32; o > 0; o >>= 1) v += __shfl_xor(v, o, 64);
        acc[e] = v;
    }
    if (lane == 0) {
        float l[E_];
        #pragma unroll
        for (int e = 0; e < E_; e++) l[e] = acc[e] + sb[e];
        int b0 = 0; float v0 = l[0];
        #pragma unroll
        for (int e = 1; e < E_; e++) if (l[e] > v0) { v0 = l[e]; b0 = e; }
        int b1 = -1; float v1 = -3.4e38f;
        #pragma unroll
        for (int e = 0; e < E_; e++) if (e != b0 && l[e] > v1) { v1 = l[e]; b1 = e; }
        float r = __expf(v1 - v0);
        float inv = 1.f / (1.f + r);
        e0a[t] = b0; e1a[t] = b1; w0a[t] = inv; w1a[t] = r * inv;
        atomicAdd(&meta[b0], 1);
        atomicAdd(&meta[b1], 1);
    }
}

// ---------------- scan: 256-padded offsets + rowtile map ----------------
// meta: [0..7]=cnt [8..15]=cursor [16..23]=padoff [24]=rows [26]=RT256 [192..235]=map256
__global__ void k_scan(int* meta)
{
    if (threadIdx.x == 0) {
        int off = 0, rt256 = 0;
        for (int e = 0; e < E_; e++) {
            meta[16 + e] = off;
            int t256 = (meta[e] + 255) / 256;
            for (int i = 0; i < t256; i++) meta[192 + rt256++] = e;
            off += t256 * 256;
        }
        meta[24] = off;
        meta[26] = rt256;
    }
}

__global__ void k_scatter(int* __restrict__ meta,
                          const int* __restrict__ e0a, const int* __restrict__ e1a,
                          const float* __restrict__ w0a, const float* __restrict__ w1a,
                          int* __restrict__ tok, float* __restrict__ gate,
                          int* __restrict__ inv)
{
    int t = blockIdx.x * 256 + threadIdx.x;
    if (t >= T_) return;
    int* cursors = meta + 8;
    const int* padoff = meta + 16;
    int e0 = e0a[t];
    int s0 = atomicAdd(&cursors[e0], 1);
    int p0 = padoff[e0] + s0;
    tok[p0] = t; gate[p0] = w0a[t]; inv[2 * t] = p0;
    int e1 = e1a[t];
    int s1 = atomicAdd(&cursors[e1], 1);
    int p1 = padoff[e1] + s1;
    tok[p1] = t; gate[p1] = w1a[t]; inv[2 * t + 1] = p1;
}

// ---------------- GEMM1 + homogeneous W2 cvt (round-13 proven) ----------------
__global__ __launch_bounds__(512, 2) void k_g1cvt2(
    const _Float16* __restrict__ xh,
    const _Float16* __restrict__ w1h, const float* __restrict__ b1,
    const _Float16* __restrict__ w3h, const float* __restrict__ b3,
    const float* __restrict__ w2, _Float16* __restrict__ w2h,
    const int* __restrict__ meta, const int* __restrict__ tok,
    _Float16* __restrict__ hbuf)
{
    const int b = blockIdx.x;
    const int tid = threadIdx.x;

    const fx4* s4 = (const fx4*)w2;
    hx8* d8 = (hx8*)w2h;
    const int cBase = b * CPB;
    const int cEnd = (cBase + CPB < N8W2) ? cBase + CPB : N8W2;

    const int g = b >> 3;
    const int r = (g >> 5) * 8 + (b & 7);
    const int c = g & 31;

    if (r >= meta[26]) {
        for (int k = 0; k < 22; ++k) {
            int idx = cBase + k * 512 + tid;
            if (idx < cEnd)
                d8[idx] = pack8(s4[2 * (size_t)idx], s4[2 * (size_t)idx + 1]);
        }
        return;
    }

    const int e = meta[192 + r];
    const int prow0 = r * 256;
    const int col0 = c * 128;

    extern __shared__ _Float16 smem[];        // 128 KiB
    _Float16* sA  = smem;                     // [2][256*64]
    _Float16* sB1 = smem + 2 * 256 * 64;      // [2][128*64]
    _Float16* sB3 = sB1 + 2 * 128 * 64;       // [2][128*64]

    const int w = tid >> 6, l = tid & 63;
    const int arow = tid >> 3;                // 0..63
    const int swizh = 8 * ((tid & 7) ^ (arow & 7));
    const int wv8 = w * 8;

    const _Float16* aSrc[4];
    #pragma unroll
    for (int p = 0; p < 4; ++p) {
        const int t = tok[prow0 + p * 64 + arow];   // pad rows -> token 0 (memset)
        aSrc[p] = xh + (size_t)t * D_ + swizh;
    }
    const _Float16* b1S = w1h + ((size_t)e * H_ + col0 + arow) * D_ + swizh;
    const _Float16* b3S = w3h + ((size_t)e * H_ + col0 + arow) * D_ + swizh;

    const int wm = w >> 2, wn = w & 3;
    const int fr = l & 15, q4 = l >> 4;

    fx4 acc1[8][2] = {}, acc3[8][2] = {};

    fx4 cA0, cB0, cA1, cB1;
    hx8 ph0, ph1;
    int pi0 = -1, pi1 = -1;
    int ci0 = -1, ci1 = -1;

    #define G1STAGE(buf, kk)                                                        \
        _Pragma("unroll")                                                           \
        for (int p = 0; p < 4; ++p)                                                 \
            gload16(aSrc[p] + (kk), &sA[(buf) * 16384 + (p * 64 + wv8) * 64]);      \
        _Pragma("unroll")                                                           \
        for (int p = 0; p < 2; ++p) {                                               \
            gload16(b1S + (size_t)(p * 64) * D_ + (kk), &sB1[(buf) * 8192 + (p * 64 + wv8) * 64]); \
            gload16(b3S + (size_t)(p * 64) * D_ + (kk), &sB3[(buf) * 8192 + (p * 64 + wv8) * 64]); \
        }

    G1STAGE(0, 0)
    asm volatile("s_waitcnt vmcnt(0)" ::: "memory");
    __builtin_amdgcn_s_barrier();

    int cur = 0;
    for (int t = 0; t < D_ / 64; ++t) {
        if (pi0 >= 0) d8[pi0] = ph0;
        if (pi1 >= 0) d8[pi1] = ph1;
        pi0 = pi1 = -1;
        if (t + 1 < D_ / 64) { G1STAGE(cur ^ 1, (t + 1) * 64) }
        ci0 = ci1 = -1;
        if (t <= 10) {
            int i0 = cBase + (2 * t) * 512 + tid;
            int i1 = cBase + (2 * t + 1) * 512 + tid;
            if (i0 < cEnd) { cA0 = s4[2 * (size_t)i0]; cB0 = s4[2 * (size_t)i0 + 1]; ci0 = i0; }
            if (i1 < cEnd) { cA1 = s4[2 * (size_t)i1]; cB1 = s4[2 * (size_t)i1 + 1]; ci1 = i1; }
        }
        hx8 bf1[2][2], bf3[2][2];
        #pragma unroll
        for (int q = 0; q < 4; ++q) {
            hx8 af[2][2];
            #pragma unroll
            for (int mi = 0; mi < 2; ++mi)
                #pragma unroll
                for (int kh = 0; kh < 2; ++kh) {
                    const int R = wm * 128 + q * 32 + mi * 16 + fr;
                    af[mi][kh] = *(const hx8*)&sA[cur * 16384 + R * 64 + 8 * (((kh << 2) + q4) ^ (R & 7))];
                }
            if (q == 0) {
                #pragma unroll
                for (int ni = 0; ni < 2; ++ni)
                    #pragma unroll
                    for (int kh = 0; kh < 2; ++kh) {
                        const int Rc = wn * 32 + ni * 16 + fr;
                        bf1[ni][kh] = *(const hx8*)&sB1[cur * 8192 + Rc * 64 + 8 * (((kh << 2) + q4) ^ (Rc & 7))];
                        bf3[ni][kh] = *(const hx8*)&sB3[cur * 8192 + Rc * 64 + 8 * (((kh << 2) + q4) ^ (Rc & 7))];
                    }
            }
            __builtin_amdgcn_s_setprio(1);
            #pragma unroll
            for (int ni = 0; ni < 2; ++ni)
                #pragma unroll
                for (int mi = 0; mi < 2; ++mi) {
                    acc1[q * 2 + mi][ni] = __builtin_amdgcn_mfma_f32_16x16x32_f16(af[mi][0], bf1[ni][0], acc1[q * 2 + mi][ni], 0, 0, 0);
                    acc1[q * 2 + mi][ni] = __builtin_amdgcn_mfma_f32_16x16x32_f16(af[mi][1], bf1[ni][1], acc1[q * 2 + mi][ni], 0, 0, 0);
                    acc3[q * 2 + mi][ni] = __builtin_amdgcn_mfma_f32_16x16x32_f16(af[mi][0], bf3[ni][0], acc3[q * 2 + mi][ni], 0, 0, 0);
                    acc3[q * 2 + mi][ni] = __builtin_amdgcn_mfma_f32_16x16x32_f16(af[mi][1], bf3[ni][1], acc3[q * 2 + mi][ni], 0, 0, 0);
                }
            __builtin_amdgcn_s_setprio(0);
        }
        if (ci0 >= 0) { ph0 = pack8(cA0, cB0); pi0 = ci0; }
        if (ci1 >= 0) { ph1 = pack8(cA1, cB1); pi1 = ci1; }
        asm volatile("s_waitcnt vmcnt(0)" ::: "memory");
        __builtin_amdgcn_s_barrier();
        cur ^= 1;
    }
    if (pi0 >= 0) d8[pi0] = ph0;
    if (pi1 >= 0) d8[pi1] = ph1;

    #pragma unroll
    for (int ni = 0; ni < 2; ++ni) {
        const int col = col0 + wn * 32 + ni * 16 + fr;
        const float bb1 = b1[(size_t)e * H_ + col];
        const float bb3 = b3[(size_t)e * H_ + col];
        #pragma unroll
        for (int rf = 0; rf < 8; ++rf) {
            const int rowb = prow0 + wm * 128 + rf * 16 + q4 * 4;
            #pragma unroll
            for (int j = 0; j < 4; ++j) {
                float v1 = acc1[rf][ni][j] + bb1;
                float v3 = acc3[rf][ni][j] + bb3;
                float hv = v1 * v3 / (1.f + __expf(-v1));
                hbuf[(size_t)(rowb + j) * H_ + col] = (_Float16)hv;
            }
        }
    }
    #undef G1STAGE
}

// ---------------- GEMM2: part = h W2^T + b2 (round-11 proven, exact) ----------------
__global__ __launch_bounds__(512, 2) void k_gemm2(
    const _Float16* __restrict__ hbuf, const _Float16* __restrict__ w2h,
    const float* __restrict__ b2, const int* __restrict__ meta,
    _Float16* __restrict__ part)
{
    const int b = blockIdx.x;
    const int g = b >> 3;
    const int r = (g >> 4) * 8 + (b & 7);
    const int c = g & 15;
    if (r >= meta[26]) return;
    const int e = meta[192 + r];
    const int prow0 = r * 256;
    const int col0 = c * 256;

    extern __shared__ _Float16 smem[];        // 128 KiB
    _Float16* sA = smem;                      // [2][256*64]
    _Float16* sB = smem + 2 * 256 * 64;       // [2][256*64]

    const int tid = threadIdx.x;
    const int w = tid >> 6, l = tid & 63;
    const int arow = tid >> 3;                // 0..63
    const int swizh = 8 * ((tid & 7) ^ (arow & 7));
    const _Float16* aS = hbuf + (size_t)(prow0 + arow) * H_ + swizh;
    const _Float16* bS = w2h + ((size_t)e * C_ + col0 + arow) * H_ + swizh;
    const int wv8 = w * 8;

    const int wm = w >> 2, wn = w & 3;
    const int fr = l & 15, q4 = l >> 4;

    fx4 acc[8][4] = {};
    hx8 bf[4][2];

    #define STG_A0(buf, kk) { gload16(aS + (size_t)(kk), &sA[(buf)*16384 + (wv8)*64]); \
                              gload16(aS + (size_t)64*H_ + (kk), &sA[(buf)*16384 + (64+wv8)*64]); }
    #define STG_A1(buf, kk) { gload16(aS + (size_t)128*H_ + (kk), &sA[(buf)*16384 + (128+wv8)*64]); \
                              gload16(aS + (size_t)192*H_ + (kk), &sA[(buf)*16384 + (192+wv8)*64]); }
    #define STG_B0(buf, kk) { gload16(bS + (size_t)(kk), &sB[(buf)*16384 + (wv8)*64]); \
                              gload16(bS + (size_t)64*H_ + (kk), &sB[(buf)*16384 + (64+wv8)*64]); }
    #define STG_B1(buf, kk) { gload16(bS + (size_t)128*H_ + (kk), &sB[(buf)*16384 + (128+wv8)*64]); \
                              gload16(bS + (size_t)192*H_ + (kk), &sB[(buf)*16384 + (192+wv8)*64]); }

    #define RD_BF(buf)                                                        \
        _Pragma("unroll")                                                     \
        for (int ni = 0; ni < 4; ++ni)                                        \
            _Pragma("unroll")                                                 \
            for (int kh = 0; kh < 2; ++kh) {                                  \
                const int Rc = wn * 64 + ni * 16 + fr;                        \
                bf[ni][kh] = *(const hx8*)&sB[(buf)*16384 + Rc * 64 + 8 * (((kh << 2) + q4) ^ (Rc & 7))]; \
            }

    #define G2PHASE(buf, q, WAITSTMT, ...) {                                  \
        hx8 af[2][2];                                                         \
        _Pragma("unroll")                                                     \
        for (int mi = 0; mi < 2; ++mi)                                        \
            _Pragma("unroll")                                                 \
            for (int kh = 0; kh < 2; ++kh) {                                  \
                const int R = wm * 128 + (q) * 32 + mi * 16 + fr;             \
                af[mi][kh] = *(const hx8*)&sA[(buf)*16384 + R * 64 + 8 * (((kh << 2) + q4) ^ (R & 7))]; \
            }                                                                 \
        __VA_ARGS__                                                           \
        __builtin_amdgcn_s_barrier();                                         \
        __builtin_amdgcn_s_setprio(1);                                        \
        _Pragma("unroll")                                                     \
        for (int ni = 0; ni < 4; ++ni)                                        \
            _Pragma("unroll")                                                 \
            for (int mi = 0; mi < 2; ++mi) {                                  \
                acc[(q)*2+mi][ni] = __builtin_amdgcn_mfma_f32_16x16x32_f16(af[mi][0], bf[ni][0], acc[(q)*2+mi][ni], 0, 0, 0); \
                acc[(q)*2+mi][ni] = __builtin_amdgcn_mfma_f32_16x16x32_f16(af[mi][1], bf[ni][1], acc[(q)*2+mi][ni], 0, 0, 0); \
            }                                                                 \
        __builtin_amdgcn_s_setprio(0);                                        \
        WAITSTMT;                                                             \
        __builtin_amdgcn_s_barrier(); }

    STG_B0(0, 0) STG_B1(0, 0) STG_A0(0, 0) STG_A1(0, 0)
    STG_B0(1, 64) STG_B1(1, 64)
    asm volatile("s_waitcnt vmcnt(4)" ::: "memory");
    __builtin_amdgcn_s_barrier();

    for (int i = 0; i < 31; ++i) {
        const int kk0 = i * 128;
        RD_BF(0)
        G2PHASE(0, 0, , STG_A0(1, kk0 + 64))
        G2PHASE(0, 1, , STG_A1(1, kk0 + 64))
        G2PHASE(0, 2, , STG_B0(0, kk0 + 128))
        G2PHASE(0, 3, asm volatile("s_waitcnt vmcnt(4)" ::: "memory"), STG_B1(0, kk0 + 128))
        RD_BF(1)
        G2PHASE(1, 0, , STG_A0(0, kk0 + 128))
        G2PHASE(1, 1, , STG_A1(0, kk0 + 128))
        G2PHASE(1, 2, , STG_B0(1, kk0 + 192))
        G2PHASE(1, 3, asm volatile("s_waitcnt vmcnt(4)" ::: "memory"), STG_B1(1, kk0 + 192))
    }
    RD_BF(0)
    G2PHASE(0, 0, , STG_A0(1, 4032))
    G2PHASE(0, 1, , STG_A1(1, 4032))
    G2PHASE(0, 2, , )
    G2PHASE(0, 3, asm volatile("s_waitcnt vmcnt(0)" ::: "memory"), )
    RD_BF(1)
    G2PHASE(1, 0, , )
    G2PHASE(1, 1, , )
    G2PHASE(1, 2, , )
    G2PHASE(1, 3, , )

    #pragma unroll
    for (int ni = 0; ni < 4; ++ni) {
        const int col = col0 + wn * 64 + ni * 16 + fr;
        const float bb = b2[(size_t)e * C_ + col];
        #pragma unroll
        for (int rf = 0; rf < 8; ++rf) {
            const int rowb = prow0 + wm * 128 + rf * 16 + q4 * 4;
            #pragma unroll
            for (int j = 0; j < 4; ++j)
                part[(size_t)(rowb + j) * C_ + col] = (_Float16)(acc[rf][ni][j] + bb);
        }
    }
    #undef STG_A0
    #undef STG_A1
    #undef STG_B0
    #undef STG_B1
    #undef RD_BF
    #undef G2PHASE
}

// ---------------- combine: out[t] = g0*part[inv0] + g1*part[inv1] ----------------
__global__ __launch_bounds__(256) void k_combine(
    const _Float16* __restrict__ part, const int* __restrict__ inv,
    const float* __restrict__ gate, float* __restrict__ out)
{
    const int bid = blockIdx.x;               // T_*2 blocks
    const int t = bid >> 1;
    const int c0 = ((bid & 1) << 11) + ((int)threadIdx.x << 3);
    const int p0 = inv[2 * t], p1 = inv[2 * t + 1];
    const float g0 = gate[p0], g1 = gate[p1];
    hx8 a = *(const hx8*)(part + (size_t)p0 * C_ + c0);
    hx8 b = *(const hx8*)(part + (size_t)p1 * C_ + c0);
    fx4 o0, o1;
    #pragma unroll
    for (int j = 0; j < 4; j++) {
        o0[j] = g0 * (float)a[j]     + g1 * (float)b[j];
        o1[j] = g0 * (float)a[4 + j] + g1 * (float)b[4 + j];
    }
    *(fx4*)(out + (size_t)t * C_ + c0)     = o0;
    *(fx4*)(out + (size_t)t * C_ + c0 + 4) = o1;
}

// ---------------- launch ----------------
extern "C" void kernel_launch(void* const* d_in, const int* in_sizes, int n_in,
                              void* d_out, int out_size, void* d_ws, size_t ws_size,
                              hipStream_t stream)
{
    const float* x  = (const float*)d_in[0];
    const float* sw = (const float*)d_in[1];
    const float* sb = (const float*)d_in[2];
    const float* w1 = (const float*)d_in[3];
    const float* b1 = (const float*)d_in[4];
    const float* w2 = (const float*)d_in[5];
    const float* b2 = (const float*)d_in[6];
    const float* w3 = (const float*)d_in[7];
    const float* b3 = (const float*)d_in[8];
    float* out = (float*)d_out;

    char* ws = (char*)d_ws;
    const size_t OFF_META = 0;                                    // 2048 B
    const size_t OFF_E0   = 2048;
    const size_t OFF_E1   = OFF_E0 + 4 * (size_t)T_;
    const size_t OFF_W0   = OFF_E1 + 4 * (size_t)T_;
    const size_t OFF_W1A  = OFF_W0 + 4 * (size_t)T_;
    const size_t OFF_TOK  = OFF_W1A + 4 * (size_t)T_;
    const size_t OFF_GATE = OFF_TOK + 4 * (size_t)PADROWS;
    const size_t OFF_INV  = OFF_GATE + 4 * (size_t)PADROWS;
    const size_t OFF_XH   = OFF_INV + 8 * (size_t)T_;
    const size_t OFF_HBUF = OFF_XH + 2 * (size_t)T_ * D_;
    // ALIAS region: w1h+w3h (live: precvt..g1cvt2) overlaps part (live: gemm2..combine)
    const size_t OFF_ALIAS = OFF_HBUF + 2 * (size_t)PADROWS * H_;
    const size_t SZ_ALIAS  = 4 * (size_t)E_ * H_ * D_;            // 128 MiB
    const size_t OFF_W2H   = OFF_ALIAS + SZ_ALIAS;

    int*      meta  = (int*)(ws + OFF_META);
    int*      e0a   = (int*)(ws + OFF_E0);
    int*      e1a   = (int*)(ws + OFF_E1);
    float*    w0a   = (float*)(ws + OFF_W0);
    float*    w1a   = (float*)(ws + OFF_W1A);
    int*      tokb  = (int*)(ws + OFF_TOK);
    float*    gateb = (float*)(ws + OFF_GATE);
    int*      invb  = (int*)(ws + OFF_INV);
    _Float16* xh    = (_Float16*)(ws + OFF_XH);
    _Float16* hbuf  = (_Float16*)(ws + OFF_HBUF);
    _Float16* w1h   = (_Float16*)(ws + OFF_ALIAS);
    _Float16* w3h   = (_Float16*)(ws + OFF_ALIAS + 2 * (size_t)E_ * H_ * D_);
    _Float16* partb = (_Float16*)(ws + OFF_ALIAS);                // reuses w1h/w3h space
    _Float16* w2h   = (_Float16*)(ws + OFF_W2H);

    hipMemsetAsync(meta, 0, 2048, stream);
    hipMemsetAsync(tokb, 0, 4 * (size_t)PADROWS, stream);

    k_precvt<<<NB_PRE, 256, 0, stream>>>(x, sw, sb, w1, w1h, w3, w3h, xh,
                                         meta, e0a, e1a, w0a, w1a);
    k_scan<<<1, 1, 0, stream>>>(meta);
    k_scatter<<<(T_ + 255) / 256, 256, 0, stream>>>(meta, e0a, e1a, w0a, w1a,
                                                    tokb, gateb, invb);
    k_g1cvt2<<<NG1, 512, 131072, stream>>>(xh, w1h, b1, w3h, b3, w2, w2h,
                                           meta, tokb, hbuf);
    k_gemm2<<<8 * 16 * ((MAXRT256 + 7) / 8), 512, 131072, stream>>>(
        hbuf, w2h, b2, meta, partb);
    k_combine<<<T_ * 2, 256, 0, stream>>>(partb, invb, gateb, out);
}

// Round 15
// 896.144 us; speedup vs baseline: 1.2563x; 1.0124x over previous
//
#include <hip/hip_runtime.h>

typedef _Float16 hx8 __attribute__((ext_vector_type(8)));
typedef _Float16 hx4 __attribute__((ext_vector_type(4)));
typedef float    fx4 __attribute__((ext_vector_type(4)));

constexpr int T_ = 4608;   // tokens = 8*576
constexpr int D_ = 1024;
constexpr int H_ = 4096;
constexpr int C_ = 4096;
constexpr int E_ = 8;
constexpr int PADROWS = T_ * 2 + E_ * 256;   // 11264 (256-padded buckets)
constexpr int MAXRT256 = 44;

constexpr int NB_ROUTE = T_ / 4;                      // 1152 route blocks (first)
constexpr int NBCV = 2048;                            // cvt blocks per matrix (w1,w3)
constexpr int NB_PRE = NB_ROUTE + 2 * NBCV;           // 5248
constexpr int NG1 = 8 * 32 * ((MAXRT256 + 7) / 8);    // 1536 gemm1 blocks
constexpr int N8W2 = E_ * C_ * H_ / 8;                // 16777216 hx8 chunks of W2
constexpr int CPB = (N8W2 + NG1 - 1) / NG1;           // 10923 chunks per block

// global -> LDS direct (16B/lane), dest = wave-uniform base + lane*16
__device__ __forceinline__ void gload16(const void* g, void* l) {
    __builtin_amdgcn_global_load_lds(
        (const __attribute__((address_space(1))) void*)g,
        (__attribute__((address_space(3))) void*)l, 16, 0, 0);
}

__device__ __forceinline__ hx8 pack8(fx4 a, fx4 b) {
    hx8 h;
    h[0]=(_Float16)a[0]; h[1]=(_Float16)a[1]; h[2]=(_Float16)a[2]; h[3]=(_Float16)a[3];
    h[4]=(_Float16)b[0]; h[5]=(_Float16)b[1]; h[6]=(_Float16)b[2]; h[7]=(_Float16)b[3];
    return h;
}

// grid-strided fp32 -> fp16 convert, 4 independent chunks per iteration (MLP x4)
template <int TPB>
__device__ __forceinline__ void cvt_ilp4(const float* __restrict__ s,
                                         _Float16* __restrict__ d,
                                         int n8, int bidx, int nblocks)
{
    const fx4* s4 = (const fx4*)s;
    hx8* d8 = (hx8*)d;
    const int S = nblocks * TPB;
    int i = bidx * TPB + (int)threadIdx.x;
    for (; i + 3 * S < n8; i += 4 * S) {
        const size_t i0 = i, i1 = i + S, i2 = i + 2 * S, i3 = i + 3 * S;
        fx4 a0 = s4[2*i0], b0 = s4[2*i0+1];
        fx4 a1 = s4[2*i1], b1 = s4[2*i1+1];
        fx4 a2 = s4[2*i2], b2 = s4[2*i2+1];
        fx4 a3 = s4[2*i3], b3 = s4[2*i3+1];
        d8[i0] = pack8(a0, b0);
        d8[i1] = pack8(a1, b1);
        d8[i2] = pack8(a2, b2);
        d8[i3] = pack8(a3, b3);
    }
    for (; i < n8; i += S) {
        fx4 a = s4[2*(size_t)i], b = s4[2*(size_t)i+1];
        d8[i] = pack8(a, b);
    }
}

// ---------------- precvt: routing (first) + W1/W3 cvt, one LDS-free launch ----------------
__global__ __launch_bounds__(256) void k_precvt(
    const float* __restrict__ x, const float* __restrict__ sw,
    const float* __restrict__ sb,
    const float* __restrict__ w1, _Float16* __restrict__ w1h,
    const float* __restrict__ w3, _Float16* __restrict__ w3h,
    _Float16* __restrict__ xh,
    int* __restrict__ meta, int* __restrict__ e0a, int* __restrict__ e1a,
    float* __restrict__ w0a, float* __restrict__ w1a)
{
    const int id = blockIdx.x;
    const int tid = threadIdx.x;

    if (id >= NB_ROUTE) {
        const int cid = id - NB_ROUTE;
        if (cid < NBCV) cvt_ilp4<256>(w1, w1h, E_ * H_ * D_ / 8, cid, NBCV);
        else            cvt_ilp4<256>(w3, w3h, E_ * H_ * D_ / 8, cid - NBCV, NBCV);
        return;
    }

    // route, vectorized fx4 (sw L2-hot; 4 cols/iter -> 9 vector loads/iter)
    const int wid = tid >> 6, lane = tid & 63;
    const int t = id * 4 + wid;
    const float* xr = x + (size_t)t * D_;
    _Float16* xhr = xh + (size_t)t * D_;

    float acc[E_] = {};
    #pragma unroll
    for (int it = 0; it < D_ / 256; ++it) {
        const int i0 = it * 256 + lane * 4;
        fx4 xv = *(const fx4*)(xr + i0);
        hx4 hv;
        hv[0] = (_Float16)xv[0]; hv[1] = (_Float16)xv[1];
        hv[2] = (_Float16)xv[2]; hv[3] = (_Float16)xv[3];
        *(hx4*)(xhr + i0) = hv;
        #pragma unroll
        for (int e = 0; e < E_; e++) {
            fx4 wv = *(const fx4*)(sw + e * D_ + i0);
            acc[e] += xv[0]*wv[0] + xv[1]*wv[1] + xv[2]*wv[2] + xv[3]*wv[3];
        }
    }
    #pragma unroll
    for (int e = 0; e < E_; e++) {
        float v = acc[e];
        #pragma unroll
        for (int o = 32; o > 0; o >>= 1) v += __shfl_xor(v, o, 64);
        acc[e] = v;
    }
    if (lane == 0) {
        float l[E_];
        #pragma unroll
        for (int e = 0; e < E_; e++) l[e] = acc[e] + sb[e];
        int b0 = 0; float v0 = l[0];
        #pragma unroll
        for (int e = 1; e < E_; e++) if (l[e] > v0) { v0 = l[e]; b0 = e; }
        int b1 = -1; float v1 = -3.4e38f;
        #pragma unroll
        for (int e = 0; e < E_; e++) if (e != b0 && l[e] > v1) { v1 = l[e]; b1 = e; }
        float r = __expf(v1 - v0);
        float inv = 1.f / (1.f + r);
        e0a[t] = b0; e1a[t] = b1; w0a[t] = inv; w1a[t] = r * inv;
        atomicAdd(&meta[b0], 1);
        atomicAdd(&meta[b1], 1);
    }
}

// ---------------- scan: 256-padded offsets + rowtile map ----------------
// meta: [0..7]=cnt [8..15]=cursor [16..23]=padoff [24]=rows [26]=RT256 [192..235]=map256
__global__ void k_scan(int* meta)
{
    if (threadIdx.x == 0) {
        int off = 0, rt256 = 0;
        for (int e = 0; e < E_; e++) {
            meta[16 + e] = off;
            int t256 = (meta[e] + 255) / 256;
            for (int i = 0; i < t256; i++) meta[192 + rt256++] = e;
            off += t256 * 256;
        }
        meta[24] = off;
        meta[26] = rt256;
    }
}

__global__ void k_scatter(int* __restrict__ meta,
                          const int* __restrict__ e0a, const int* __restrict__ e1a,
                          const float* __restrict__ w0a, const float* __restrict__ w1a,
                          int* __restrict__ tok, float* __restrict__ gate,
                          int* __restrict__ inv)
{
    int t = blockIdx.x * 256 + threadIdx.x;
    if (t >= T_) return;
    int* cursors = meta + 8;
    const int* padoff = meta + 16;
    int e0 = e0a[t];
    int s0 = atomicAdd(&cursors[e0], 1);
    int p0 = padoff[e0] + s0;
    tok[p0] = t; gate[p0] = w0a[t]; inv[2 * t] = p0;
    int e1 = e1a[t];
    int s1 = atomicAdd(&cursors[e1], 1);
    int p1 = padoff[e1] + s1;
    tok[p1] = t; gate[p1] = w1a[t]; inv[2 * t + 1] = p1;
}

// ---------------- GEMM1 + homogeneous W2 cvt (round-13/14 proven) ----------------
__global__ __launch_bounds__(512, 2) void k_g1cvt2(
    const _Float16* __restrict__ xh,
    const _Float16* __restrict__ w1h, const float* __restrict__ b1,
    const _Float16* __restrict__ w3h, const float* __restrict__ b3,
    const float* __restrict__ w2, _Float16* __restrict__ w2h,
    const int* __restrict__ meta, const int* __restrict__ tok,
    _Float16* __restrict__ hbuf)
{
    const int b = blockIdx.x;
    const int tid = threadIdx.x;

    const fx4* s4 = (const fx4*)w2;
    hx8* d8 = (hx8*)w2h;
    const int cBase = b * CPB;
    const int cEnd = (cBase + CPB < N8W2) ? cBase + CPB : N8W2;

    const int g = b >> 3;
    const int r = (g >> 5) * 8 + (b & 7);
    const int c = g & 31;

    if (r >= meta[26]) {
        for (int k = 0; k < 22; ++k) {
            int idx = cBase + k * 512 + tid;
            if (idx < cEnd)
                d8[idx] = pack8(s4[2 * (size_t)idx], s4[2 * (size_t)idx + 1]);
        }
        return;
    }

    const int e = meta[192 + r];
    const int prow0 = r * 256;
    const int col0 = c * 128;

    extern __shared__ _Float16 smem[];        // 128 KiB
    _Float16* sA  = smem;                     // [2][256*64]
    _Float16* sB1 = smem + 2 * 256 * 64;      // [2][128*64]
    _Float16* sB3 = sB1 + 2 * 128 * 64;       // [2][128*64]

    const int w = tid >> 6, l = tid & 63;
    const int arow = tid >> 3;                // 0..63
    const int swizh = 8 * ((tid & 7) ^ (arow & 7));
    const int wv8 = w * 8;

    const _Float16* aSrc[4];
    #pragma unroll
    for (int p = 0; p < 4; ++p) {
        const int t = tok[prow0 + p * 64 + arow];   // pad rows -> token 0 (memset)
        aSrc[p] = xh + (size_t)t * D_ + swizh;
    }
    const _Float16* b1S = w1h + ((size_t)e * H_ + col0 + arow) * D_ + swizh;
    const _Float16* b3S = w3h + ((size_t)e * H_ + col0 + arow) * D_ + swizh;

    const int wm = w >> 2, wn = w & 3;
    const int fr = l & 15, q4 = l >> 4;

    fx4 acc1[8][2] = {}, acc3[8][2] = {};

    fx4 cA0, cB0, cA1, cB1;
    hx8 ph0, ph1;
    int pi0 = -1, pi1 = -1;
    int ci0 = -1, ci1 = -1;

    #define G1STAGE(buf, kk)                                                        \
        _Pragma("unroll")                                                           \
        for (int p = 0; p < 4; ++p)                                                 \
            gload16(aSrc[p] + (kk), &sA[(buf) * 16384 + (p * 64 + wv8) * 64]);      \
        _Pragma("unroll")                                                           \
        for (int p = 0; p < 2; ++p) {                                               \
            gload16(b1S + (size_t)(p * 64) * D_ + (kk), &sB1[(buf) * 8192 + (p * 64 + wv8) * 64]); \
            gload16(b3S + (size_t)(p * 64) * D_ + (kk), &sB3[(buf) * 8192 + (p * 64 + wv8) * 64]); \
        }

    G1STAGE(0, 0)
    asm volatile("s_waitcnt vmcnt(0)" ::: "memory");
    __builtin_amdgcn_s_barrier();

    int cur = 0;
    for (int t = 0; t < D_ / 64; ++t) {
        if (pi0 >= 0) d8[pi0] = ph0;
        if (pi1 >= 0) d8[pi1] = ph1;
        pi0 = pi1 = -1;
        if (t + 1 < D_ / 64) { G1STAGE(cur ^ 1, (t + 1) * 64) }
        ci0 = ci1 = -1;
        if (t <= 10) {
            int i0 = cBase + (2 * t) * 512 + tid;
            int i1 = cBase + (2 * t + 1) * 512 + tid;
            if (i0 < cEnd) { cA0 = s4[2 * (size_t)i0]; cB0 = s4[2 * (size_t)i0 + 1]; ci0 = i0; }
            if (i1 < cEnd) { cA1 = s4[2 * (size_t)i1]; cB1 = s4[2 * (size_t)i1 + 1]; ci1 = i1; }
        }
        hx8 bf1[2][2], bf3[2][2];
        #pragma unroll
        for (int q = 0; q < 4; ++q) {
            hx8 af[2][2];
            #pragma unroll
            for (int mi = 0; mi < 2; ++mi)
                #pragma unroll
                for (int kh = 0; kh < 2; ++kh) {
                    const int R = wm * 128 + q * 32 + mi * 16 + fr;
                    af[mi][kh] = *(const hx8*)&sA[cur * 16384 + R * 64 + 8 * (((kh << 2) + q4) ^ (R & 7))];
                }
            if (q == 0) {
                #pragma unroll
                for (int ni = 0; ni < 2; ++ni)
                    #pragma unroll
                    for (int kh = 0; kh < 2; ++kh) {
                        const int Rc = wn * 32 + ni * 16 + fr;
                        bf1[ni][kh] = *(const hx8*)&sB1[cur * 8192 + Rc * 64 + 8 * (((kh << 2) + q4) ^ (Rc & 7))];
                        bf3[ni][kh] = *(const hx8*)&sB3[cur * 8192 + Rc * 64 + 8 * (((kh << 2) + q4) ^ (Rc & 7))];
                    }
            }
            __builtin_amdgcn_s_setprio(1);
            #pragma unroll
            for (int ni = 0; ni < 2; ++ni)
                #pragma unroll
                for (int mi = 0; mi < 2; ++mi) {
                    acc1[q * 2 + mi][ni] = __builtin_amdgcn_mfma_f32_16x16x32_f16(af[mi][0], bf1[ni][0], acc1[q * 2 + mi][ni], 0, 0, 0);
                    acc1[q * 2 + mi][ni] = __builtin_amdgcn_mfma_f32_16x16x32_f16(af[mi][1], bf1[ni][1], acc1[q * 2 + mi][ni], 0, 0, 0);
                    acc3[q * 2 + mi][ni] = __builtin_amdgcn_mfma_f32_16x16x32_f16(af[mi][0], bf3[ni][0], acc3[q * 2 + mi][ni], 0, 0, 0);
                    acc3[q * 2 + mi][ni] = __builtin_amdgcn_mfma_f32_16x16x32_f16(af[mi][1], bf3[ni][1], acc3[q * 2 + mi][ni], 0, 0, 0);
                }
            __builtin_amdgcn_s_setprio(0);
        }
        if (ci0 >= 0) { ph0 = pack8(cA0, cB0); pi0 = ci0; }
        if (ci1 >= 0) { ph1 = pack8(cA1, cB1); pi1 = ci1; }
        asm volatile("s_waitcnt vmcnt(0)" ::: "memory");
        __builtin_amdgcn_s_barrier();
        cur ^= 1;
    }
    if (pi0 >= 0) d8[pi0] = ph0;
    if (pi1 >= 0) d8[pi1] = ph1;

    #pragma unroll
    for (int ni = 0; ni < 2; ++ni) {
        const int col = col0 + wn * 32 + ni * 16 + fr;
        const float bb1 = b1[(size_t)e * H_ + col];
        const float bb3 = b3[(size_t)e * H_ + col];
        #pragma unroll
        for (int rf = 0; rf < 8; ++rf) {
            const int rowb = prow0 + wm * 128 + rf * 16 + q4 * 4;
            #pragma unroll
            for (int j = 0; j < 4; ++j) {
                float v1 = acc1[rf][ni][j] + bb1;
                float v3 = acc3[rf][ni][j] + bb3;
                float hv = v1 * v3 / (1.f + __expf(-v1));
                hbuf[(size_t)(rowb + j) * H_ + col] = (_Float16)hv;
            }
        }
    }
    #undef G1STAGE
}

// ---------------- GEMM2: part = h W2^T + b2 (round-11 proven, exact) ----------------
__global__ __launch_bounds__(512, 2) void k_gemm2(
    const _Float16* __restrict__ hbuf, const _Float16* __restrict__ w2h,
    const float* __restrict__ b2, const int* __restrict__ meta,
    _Float16* __restrict__ part)
{
    const int b = blockIdx.x;
    const int g = b >> 3;
    const int r = (g >> 4) * 8 + (b & 7);
    const int c = g & 15;
    if (r >= meta[26]) return;
    const int e = meta[192 + r];
    const int prow0 = r * 256;
    const int col0 = c * 256;

    extern __shared__ _Float16 smem[];        // 128 KiB
    _Float16* sA = smem;                      // [2][256*64]
    _Float16* sB = smem + 2 * 256 * 64;       // [2][256*64]

    const int tid = threadIdx.x;
    const int w = tid >> 6, l = tid & 63;
    const int arow = tid >> 3;                // 0..63
    const int swizh = 8 * ((tid & 7) ^ (arow & 7));
    const _Float16* aS = hbuf + (size_t)(prow0 + arow) * H_ + swizh;
    const _Float16* bS = w2h + ((size_t)e * C_ + col0 + arow) * H_ + swizh;
    const int wv8 = w * 8;

    const int wm = w >> 2, wn = w & 3;
    const int fr = l & 15, q4 = l >> 4;

    fx4 acc[8][4] = {};
    hx8 bf[4][2];

    #define STG_A0(buf, kk) { gload16(aS + (size_t)(kk), &sA[(buf)*16384 + (wv8)*64]); \
                              gload16(aS + (size_t)64*H_ + (kk), &sA[(buf)*16384 + (64+wv8)*64]); }
    #define STG_A1(buf, kk) { gload16(aS + (size_t)128*H_ + (kk), &sA[(buf)*16384 + (128+wv8)*64]); \
                              gload16(aS + (size_t)192*H_ + (kk), &sA[(buf)*16384 + (192+wv8)*64]); }
    #define STG_B0(buf, kk) { gload16(bS + (size_t)(kk), &sB[(buf)*16384 + (wv8)*64]); \
                              gload16(bS + (size_t)64*H_ + (kk), &sB[(buf)*16384 + (64+wv8)*64]); }
    #define STG_B1(buf, kk) { gload16(bS + (size_t)128*H_ + (kk), &sB[(buf)*16384 + (128+wv8)*64]); \
                              gload16(bS + (size_t)192*H_ + (kk), &sB[(buf)*16384 + (192+wv8)*64]); }

    #define RD_BF(buf)                                                        \
        _Pragma("unroll")                                                     \
        for (int ni = 0; ni < 4; ++ni)                                        \
            _Pragma("unroll")                                                 \
            for (int kh = 0; kh < 2; ++kh) {                                  \
                const int Rc = wn * 64 + ni * 16 + fr;                        \
                bf[ni][kh] = *(const hx8*)&sB[(buf)*16384 + Rc * 64 + 8 * (((kh << 2) + q4) ^ (Rc & 7))]; \
            }

    #define G2PHASE(buf, q, WAITSTMT, ...) {                                  \
        hx8 af[2][2];                                                         \
        _Pragma("unroll")                                                     \
        for (int mi = 0; mi < 2; ++mi)                                        \
            _Pragma("unroll")                                                 \
            for (int kh = 0; kh < 2; ++kh) {                                  \
                const int R = wm * 128 + (q) * 32 + mi * 16 + fr;             \
                af[mi][kh] = *(const hx8*)&sA[(buf)*16384 + R * 64 + 8 * (((kh << 2) + q4) ^ (R & 7))]; \
            }                                                                 \
        __VA_ARGS__                                                           \
        __builtin_amdgcn_s_barrier();                                         \
        __builtin_amdgcn_s_setprio(1);                                        \
        _Pragma("unroll")                                                     \
        for (int ni = 0; ni < 4; ++ni)                                        \
            _Pragma("unroll")                                                 \
            for (int mi = 0; mi < 2; ++mi) {                                  \
                acc[(q)*2+mi][ni] = __builtin_amdgcn_mfma_f32_16x16x32_f16(af[mi][0], bf[ni][0], acc[(q)*2+mi][ni], 0, 0, 0); \
                acc[(q)*2+mi][ni] = __builtin_amdgcn_mfma_f32_16x16x32_f16(af[mi][1], bf[ni][1], acc[(q)*2+mi][ni], 0, 0, 0); \
            }                                                                 \
        __builtin_amdgcn_s_setprio(0);                                        \
        WAITSTMT;                                                             \
        __builtin_amdgcn_s_barrier(); }

    STG_B0(0, 0) STG_B1(0, 0) STG_A0(0, 0) STG_A1(0, 0)
    STG_B0(1, 64) STG_B1(1, 64)
    asm volatile("s_waitcnt vmcnt(4)" ::: "memory");
    __builtin_amdgcn_s_barrier();

    for (int i = 0; i < 31; ++i) {
        const int kk0 = i * 128;
        RD_BF(0)
        G2PHASE(0, 0, , STG_A0(1, kk0 + 64))
        G2PHASE(0, 1, , STG_A1(1, kk0 + 64))
        G2PHASE(0, 2, , STG_B0(0, kk0 + 128))
        G2PHASE(0, 3, asm volatile("s_waitcnt vmcnt(4)" ::: "memory"), STG_B1(0, kk0 + 128))
        RD_BF(1)
        G2PHASE(1, 0, , STG_A0(0, kk0 + 128))
        G2PHASE(1, 1, , STG_A1(0, kk0 + 128))
        G2PHASE(1, 2, , STG_B0(1, kk0 + 192))
        G2PHASE(1, 3, asm volatile("s_waitcnt vmcnt(4)" ::: "memory"), STG_B1(1, kk0 + 192))
    }
    RD_BF(0)
    G2PHASE(0, 0, , STG_A0(1, 4032))
    G2PHASE(0, 1, , STG_A1(1, 4032))
    G2PHASE(0, 2, , )
    G2PHASE(0, 3, asm volatile("s_waitcnt vmcnt(0)" ::: "memory"), )
    RD_BF(1)
    G2PHASE(1, 0, , )
    G2PHASE(1, 1, , )
    G2PHASE(1, 2, , )
    G2PHASE(1, 3, , )

    #pragma unroll
    for (int ni = 0; ni < 4; ++ni) {
        const int col = col0 + wn * 64 + ni * 16 + fr;
        const float bb = b2[(size_t)e * C_ + col];
        #pragma unroll
        for (int rf = 0; rf < 8; ++rf) {
            const int rowb = prow0 + wm * 128 + rf * 16 + q4 * 4;
            #pragma unroll
            for (int j = 0; j < 4; ++j)
                part[(size_t)(rowb + j) * C_ + col] = (_Float16)(acc[rf][ni][j] + bb);
        }
    }
    #undef STG_A0
    #undef STG_A1
    #undef STG_B0
    #undef STG_B1
    #undef RD_BF
    #undef G2PHASE
}

// ---------------- combine: out[t] = g0*part[inv0] + g1*part[inv1] ----------------
__global__ __launch_bounds__(256) void k_combine(
    const _Float16* __restrict__ part, const int* __restrict__ inv,
    const float* __restrict__ gate, float* __restrict__ out)
{
    const int bid = blockIdx.x;               // T_*2 blocks
    const int t = bid >> 1;
    const int c0 = ((bid & 1) << 11) + ((int)threadIdx.x << 3);
    const int p0 = inv[2 * t], p1 = inv[2 * t + 1];
    const float g0 = gate[p0], g1 = gate[p1];
    hx8 a = *(const hx8*)(part + (size_t)p0 * C_ + c0);
    hx8 b = *(const hx8*)(part + (size_t)p1 * C_ + c0);
    fx4 o0, o1;
    #pragma unroll
    for (int j = 0; j < 4; j++) {
        o0[j] = g0 * (float)a[j]     + g1 * (float)b[j];
        o1[j] = g0 * (float)a[4 + j] + g1 * (float)b[4 + j];
    }
    *(fx4*)(out + (size_t)t * C_ + c0)     = o0;
    *(fx4*)(out + (size_t)t * C_ + c0 + 4) = o1;
}

// ---------------- launch ----------------
extern "C" void kernel_launch(void* const* d_in, const int* in_sizes, int n_in,
                              void* d_out, int out_size, void* d_ws, size_t ws_size,
                              hipStream_t stream)
{
    const float* x  = (const float*)d_in[0];
    const float* sw = (const float*)d_in[1];
    const float* sb = (const float*)d_in[2];
    const float* w1 = (const float*)d_in[3];
    const float* b1 = (const float*)d_in[4];
    const float* w2 = (const float*)d_in[5];
    const float* b2 = (const float*)d_in[6];
    const float* w3 = (const float*)d_in[7];
    const float* b3 = (const float*)d_in[8];
    float* out = (float*)d_out;

    char* ws = (char*)d_ws;
    const size_t OFF_META = 0;                                    // 2048 B
    const size_t OFF_E0   = 2048;
    const size_t OFF_E1   = OFF_E0 + 4 * (size_t)T_;
    const size_t OFF_W0   = OFF_E1 + 4 * (size_t)T_;
    const size_t OFF_W1A  = OFF_W0 + 4 * (size_t)T_;
    const size_t OFF_TOK  = OFF_W1A + 4 * (size_t)T_;
    const size_t OFF_GATE = OFF_TOK + 4 * (size_t)PADROWS;
    const size_t OFF_INV  = OFF_GATE + 4 * (size_t)PADROWS;
    const size_t OFF_XH   = OFF_INV + 8 * (size_t)T_;
    const size_t OFF_HBUF = OFF_XH + 2 * (size_t)T_ * D_;
    // ALIAS region: w1h+w3h (live: precvt..g1cvt2) overlaps part (live: gemm2..combine)
    const size_t OFF_ALIAS = OFF_HBUF + 2 * (size_t)PADROWS * H_;
    const size_t SZ_ALIAS  = 4 * (size_t)E_ * H_ * D_;            // 128 MiB
    const size_t OFF_W2H   = OFF_ALIAS + SZ_ALIAS;

    int*      meta  = (int*)(ws + OFF_META);
    int*      e0a   = (int*)(ws + OFF_E0);
    int*      e1a   = (int*)(ws + OFF_E1);
    float*    w0a   = (float*)(ws + OFF_W0);
    float*    w1a   = (float*)(ws + OFF_W1A);
    int*      tokb  = (int*)(ws + OFF_TOK);
    float*    gateb = (float*)(ws + OFF_GATE);
    int*      invb  = (int*)(ws + OFF_INV);
    _Float16* xh    = (_Float16*)(ws + OFF_XH);
    _Float16* hbuf  = (_Float16*)(ws + OFF_HBUF);
    _Float16* w1h   = (_Float16*)(ws + OFF_ALIAS);
    _Float16* w3h   = (_Float16*)(ws + OFF_ALIAS + 2 * (size_t)E_ * H_ * D_);
    _Float16* partb = (_Float16*)(ws + OFF_ALIAS);                // reuses w1h/w3h space
    _Float16* w2h   = (_Float16*)(ws + OFF_W2H);

    hipMemsetAsync(meta, 0, 2048, stream);
    hipMemsetAsync(tokb, 0, 4 * (size_t)PADROWS, stream);

    k_precvt<<<NB_PRE, 256, 0, stream>>>(x, sw, sb, w1, w1h, w3, w3h, xh,
                                         meta, e0a, e1a, w0a, w1a);
    k_scan<<<1, 1, 0, stream>>>(meta);
    k_scatter<<<(T_ + 255) / 256, 256, 0, stream>>>(meta, e0a, e1a, w0a, w1a,
                                                    tokb, gateb, invb);
    k_g1cvt2<<<NG1, 512, 131072, stream>>>(xh, w1h, b1, w3h, b3, w2, w2h,
                                           meta, tokb, hbuf);
    k_gemm2<<<8 * 16 * ((MAXRT256 + 7) / 8), 512, 131072, stream>>>(
        hbuf, w2h, b2, meta, partb);
    k_combine<<<T_ * 2, 256, 0, stream>>>(partb, invb, gateb, out);
}